// Round 1
// baseline (3337.936 us; speedup 1.0000x reference)
//
#include <hip/hip_runtime.h>
#include <hip/hip_bf16.h>
#include <cstdint>

#define NN 50000      // nodes
#define NE 500000     // edges
#define NR 4          // relations
#define NBATCH 512    // graphs
#define HD 256        // hidden/out width

__constant__ int c_off[6] = {0,33,38,41,45,47};   // cumulative CARD offsets (total 50)

__device__ __forceinline__ float sigf(float x){ return 1.0f/(1.0f+__expf(-x)); }

// ---------- folded weight precompute:  out[rc][h] = emb_j[cl] . W[r, j*64.. , h] ----------
__global__ void k_weff(const float* __restrict__ e0,const float* __restrict__ e1,
                       const float* __restrict__ e2,const float* __restrict__ e3,
                       const float* __restrict__ e4,const float* __restrict__ e5,
                       const float* __restrict__ W, int rstride,
                       float* __restrict__ out){
  int rc = blockIdx.x, h = threadIdx.x;
  int r = rc/50, cg = rc%50;
  int j, cl;
  if      (cg>=47){j=5;cl=cg-47;} else if (cg>=45){j=4;cl=cg-45;}
  else if (cg>=41){j=3;cl=cg-41;} else if (cg>=38){j=2;cl=cg-38;}
  else if (cg>=33){j=1;cl=cg-33;} else            {j=0;cl=cg;}
  const float* emb = j==0?e0:j==1?e1:j==2?e2:j==3?e3:j==4?e4:e5;
  const float* wb = W + (size_t)r*rstride + (size_t)(j*64)*HD + h;
  float acc = 0.f;
  #pragma unroll 8
  for (int k=0;k<64;k++) acc += emb[cl*64+k]*wb[(size_t)k*HD];
  out[(size_t)rc*HD+h] = acc;
}

// ---------- per-(dst,rel) histogram of source categorical features ----------
__global__ void k_hist(const int* __restrict__ ei, const int* __restrict__ et,
                       const int* __restrict__ x, int* __restrict__ hist,
                       int* __restrict__ cnt){
  int e = blockIdx.x*256 + threadIdx.x;
  if (e >= NE) return;
  int s = ei[e], d = ei[NE+e], t = et[e];
  int seg = d*NR + t;
  atomicAdd(&cnt[seg], 1);
  int base = seg*50;
  #pragma unroll
  for (int j=0;j<6;j++){
    int c = x[s*6+j];
    atomicAdd(&hist[base + c_off[j] + c], 1);
  }
}

__global__ void k_invc(const int* __restrict__ cnt, float* __restrict__ invc){
  int i = blockIdx.x*256 + threadIdx.x;
  if (i >= NN*NR) return;
  invc[i] = 1.0f / fmaxf((float)cnt[i], 1.0f);
}

// ---------- layer 1: h1 = sigmoid( b1 + root-lookups + sum_r (hist/cnt) @ W1eff ) ----------
__global__ void k_layer1(const int* __restrict__ x, const int* __restrict__ hist,
                         const float* __restrict__ invc, const float* __restrict__ W1eff,
                         const float* __restrict__ R1eff, const float* __restrict__ b1,
                         float* __restrict__ h1){
  __shared__ int sh[200];
  __shared__ float siv[4];
  int n = blockIdx.x, tid = threadIdx.x;
  if (tid < 200) sh[tid] = hist[(size_t)n*200 + tid];
  if (tid >= 200 && tid < 204) siv[tid-200] = invc[n*4 + tid - 200];
  __syncthreads();
  float acc = b1[tid];
  #pragma unroll
  for (int j=0;j<6;j++){
    int cg = c_off[j] + x[n*6+j];
    acc += R1eff[(size_t)cg*HD + tid];
  }
  for (int r=0;r<4;r++){
    float iv = siv[r];
    for (int c=0;c<50;c++){
      int w = sh[r*50+c];
      if (w) acc += ((float)w*iv) * W1eff[(size_t)(r*50+c)*HD + tid];
    }
  }
  h1[(size_t)n*HD + tid] = sigf(acc);
}

// ---------- edge scatter for one relation: buf[dst] += h1[src] ----------
__global__ void k_scatter(const int* __restrict__ ei, const int* __restrict__ et,
                          const float* __restrict__ h1, float* __restrict__ buf, int r){
  int t = threadIdx.x;
  int e = blockIdx.x*4 + (t>>6);
  int lane = t & 63;
  if (e >= NE) return;
  if (et[e] != r) return;
  int s = ei[e], d = ei[NE+e];
  const float4 v = *(const float4*)(h1 + (size_t)s*HD + lane*4);
  float* dst = buf + (size_t)d*HD + lane*4;
  atomicAdd(dst+0, v.x); atomicAdd(dst+1, v.y);
  atomicAdd(dst+2, v.z); atomicAdd(dst+3, v.w);
}

// ---------- fp32 tiled GEMM: C[M,256] (=/+)= rowscale(A[M,K]) @ B[K,256] (+bias) ----------
__global__ __launch_bounds__(256) void k_gemm(
    const float* __restrict__ A, const float* __restrict__ B, float* __restrict__ C,
    int M, int K,
    const float* __restrict__ rs, int rsStride, int rsOff,
    const float* __restrict__ bias, int acc_flag){
  __shared__ float As[16][68];   // [k][m]
  __shared__ float Bs[16][68];   // [k][n]
  int bm = blockIdx.y*64, bn = blockIdx.x*64;
  int tid = threadIdx.x;
  int tx = tid & 15, ty = tid >> 4;
  float acc[4][4] = {};
  int lm = tid >> 2;           // A row within tile
  int lk = (tid & 3) * 4;      // A k within tile
  int brow = tid >> 4;         // B k row
  int bcol = (tid & 15) * 4;   // B col
  for (int k0 = 0; k0 < K; k0 += 16){
    int arow = bm + lm; if (arow >= M) arow = M-1;
    float4 av = *(const float4*)(A + (size_t)arow*K + k0 + lk);
    As[lk+0][lm]=av.x; As[lk+1][lm]=av.y; As[lk+2][lm]=av.z; As[lk+3][lm]=av.w;
    float4 bv = *(const float4*)(B + (size_t)(k0+brow)*HD + bn + bcol);
    *(float4*)&Bs[brow][bcol] = bv;
    __syncthreads();
    #pragma unroll
    for (int kk=0;kk<16;kk++){
      float4 a4 = *(const float4*)&As[kk][ty*4];
      float4 b4 = *(const float4*)&Bs[kk][tx*4];
      acc[0][0]+=a4.x*b4.x; acc[0][1]+=a4.x*b4.y; acc[0][2]+=a4.x*b4.z; acc[0][3]+=a4.x*b4.w;
      acc[1][0]+=a4.y*b4.x; acc[1][1]+=a4.y*b4.y; acc[1][2]+=a4.y*b4.z; acc[1][3]+=a4.y*b4.w;
      acc[2][0]+=a4.z*b4.x; acc[2][1]+=a4.z*b4.y; acc[2][2]+=a4.z*b4.z; acc[2][3]+=a4.z*b4.w;
      acc[3][0]+=a4.w*b4.x; acc[3][1]+=a4.w*b4.y; acc[3][2]+=a4.w*b4.z; acc[3][3]+=a4.w*b4.w;
    }
    __syncthreads();
  }
  for (int i=0;i<4;i++){
    int row = bm + ty*4 + i;
    if (row >= M) continue;
    float s = rs ? rs[(size_t)row*rsStride + rsOff] : 1.0f;
    #pragma unroll
    for (int j=0;j<4;j++){
      int col = bn + tx*4 + j;
      float v = acc[i][j] * s;
      if (bias) v += bias[col];
      float* cp = &C[(size_t)row*HD + col];
      if (acc_flag) *cp += v; else *cp = v;
    }
  }
}

__global__ void k_sigmoid(float* __restrict__ a, int n4){
  int i = blockIdx.x*256 + threadIdx.x;
  if (i >= n4) return;
  float4 v = ((float4*)a)[i];
  v.x=sigf(v.x); v.y=sigf(v.y); v.z=sigf(v.z); v.w=sigf(v.w);
  ((float4*)a)[i]=v;
}

// ---------- BN stats (training-mode, biased var) ----------
__global__ void k_bnstats(const float* __restrict__ g, float* __restrict__ chan){
  int c = threadIdx.x;
  int r0 = blockIdx.x*128;
  int rend = min(r0+128, NN);
  float s=0.f, q=0.f;
  for (int row=r0; row<rend; row++){
    float v = g[(size_t)row*HD + c];
    s += v; q += v*v;
  }
  atomicAdd(&chan[c], s); atomicAdd(&chan[HD+c], q);
}

__global__ void k_bnfin(const float* __restrict__ chan, const float* __restrict__ bng,
                        const float* __restrict__ bnb, float* __restrict__ bnp){
  int c = threadIdx.x;
  float mu = chan[c]/(float)NN;
  float var = chan[HD+c]/(float)NN - mu*mu;
  float scale = bng[c]*rsqrtf(var + 1e-5f);
  bnp[c] = bnb[c] - mu*scale;     // shift
  bnp[HD+c] = scale;              // scale
}

__device__ __forceinline__ unsigned fenc(float f){
  unsigned u = __float_as_uint(f);
  return (u & 0x80000000u) ? ~u : (u | 0x80000000u);
}
__device__ __forceinline__ float fdec(unsigned k){
  return (k & 0x80000000u) ? __uint_as_float(k & 0x7fffffffu) : __uint_as_float(~k);
}

// ---------- gate = relu(BN(g)) . g2_w + g2_b ; atomic segment max ----------
__global__ void k_gate(const float* __restrict__ g, const float* __restrict__ bnp,
                       const float* __restrict__ g2w, const float* __restrict__ g2b,
                       const int* __restrict__ batch, float* __restrict__ gate,
                       unsigned* __restrict__ gmaxk){
  int lane = threadIdx.x & 63;
  int n = blockIdx.x*4 + (threadIdx.x>>6);
  if (n >= NN) return;
  float s = 0.f;
  #pragma unroll
  for (int k=0;k<4;k++){
    int c = lane + k*64;
    float v = g[(size_t)n*HD + c]*bnp[HD+c] + bnp[c];
    v = fmaxf(v, 0.f);
    s += v * g2w[c];
  }
  #pragma unroll
  for (int o=32;o>0;o>>=1) s += __shfl_down(s, o);
  if (lane==0){
    float gt = s + g2b[0];
    gate[n] = gt;
    atomicMax(&gmaxk[batch[n]], fenc(gt));
  }
}

__global__ void k_exp(const float* __restrict__ gate, const unsigned* __restrict__ gmaxk,
                      const int* __restrict__ batch, float* __restrict__ expv,
                      float* __restrict__ denom){
  int n = blockIdx.x*256 + threadIdx.x;
  if (n >= NN) return;
  int b = batch[n];
  float e = __expf(gate[n] - fdec(gmaxk[b]));
  expv[n] = e;
  atomicAdd(&denom[b], e);
}

__global__ void k_pool(const float* __restrict__ h2, const float* __restrict__ expv,
                       const float* __restrict__ denom, const int* __restrict__ batch,
                       float* __restrict__ pooled){
  int lane = threadIdx.x & 63;
  int n = blockIdx.x*4 + (threadIdx.x>>6);
  if (n >= NN) return;
  int b = batch[n];
  float w = expv[n] / (denom[b] + 1e-16f);
  float4 v = *(const float4*)(h2 + (size_t)n*HD + lane*4);
  float* dst = pooled + (size_t)b*HD + lane*4;
  atomicAdd(dst+0, w*v.x); atomicAdd(dst+1, w*v.y);
  atomicAdd(dst+2, w*v.z); atomicAdd(dst+3, w*v.w);
}

__global__ void k_out(const float* __restrict__ pooled, const float* __restrict__ glw,
                      const float* __restrict__ glb, float* __restrict__ out){
  int lane = threadIdx.x & 63;
  int b = blockIdx.x*4 + (threadIdx.x>>6);
  if (b >= NBATCH) return;
  float s = 0.f;
  #pragma unroll
  for (int k=0;k<4;k++){
    int c = lane + k*64;
    s += pooled[(size_t)b*HD + c]*glw[c];
  }
  #pragma unroll
  for (int o=32;o>0;o>>=1) s += __shfl_down(s, o);
  if (lane==0) out[b] = sigf(s + glb[0]);
}

extern "C" void kernel_launch(void* const* d_in, const int* in_sizes, int n_in,
                              void* d_out, int out_size, void* d_ws, size_t ws_size,
                              hipStream_t stream) {
  const int* x     = (const int*)d_in[0];
  const int* ei    = (const int*)d_in[1];
  const int* et    = (const int*)d_in[2];
  const int* batch = (const int*)d_in[3];
  const float* emb0 = (const float*)d_in[4];
  const float* emb1 = (const float*)d_in[5];
  const float* emb2 = (const float*)d_in[6];
  const float* emb3 = (const float*)d_in[7];
  const float* emb4 = (const float*)d_in[8];
  const float* emb5 = (const float*)d_in[9];
  const float* W1    = (const float*)d_in[10];
  const float* root1 = (const float*)d_in[11];
  const float* b1    = (const float*)d_in[12];
  const float* W2    = (const float*)d_in[13];
  const float* root2 = (const float*)d_in[14];
  const float* b2    = (const float*)d_in[15];
  const float* g1w   = (const float*)d_in[16];
  const float* g1b   = (const float*)d_in[17];
  const float* bng   = (const float*)d_in[18];
  const float* bnb   = (const float*)d_in[19];
  const float* g2w   = (const float*)d_in[20];
  const float* g2b   = (const float*)d_in[21];
  const float* glw   = (const float*)d_in[22];
  const float* glb   = (const float*)d_in[23];
  float* out = (float*)d_out;

  // ---- workspace carve-up (256B aligned) ----
  char* w = (char*)d_ws;
  auto alloc = [&](size_t bytes)->char* {
    char* p = w; w += (bytes + 255) & ~(size_t)255; return p;
  };
  const size_t N256 = (size_t)NN*HD*sizeof(float);          // 51.2 MB
  float* h1   = (float*)alloc(N256);                        // layer1 out; later g
  float* hC   = (float*)alloc(N256);                        // h2 accumulator / h2
  float* hS   = (float*)alloc(N256);                        // scatter buf; hist aliased (40MB<51.2MB)
  int*   hist = (int*)hS;
  float* invc = (float*)alloc((size_t)NN*NR*sizeof(float));
  int*   cnt  = (int*)alloc((size_t)NN*NR*sizeof(int));
  float* W1eff= (float*)alloc((size_t)NR*50*HD*sizeof(float));
  float* R1eff= (float*)alloc((size_t)50*HD*sizeof(float));
  float* gate = (float*)alloc((size_t)NN*sizeof(float));
  float* expv = (float*)alloc((size_t)NN*sizeof(float));
  float* chan = (float*)alloc((size_t)2*HD*sizeof(float));
  float* bnp  = (float*)alloc((size_t)2*HD*sizeof(float));
  unsigned* gmaxk = (unsigned*)alloc((size_t)NBATCH*sizeof(unsigned));
  float* denom    = (float*)alloc((size_t)NBATCH*sizeof(float));
  float* pooled   = (float*)alloc((size_t)NBATCH*HD*sizeof(float));

  // ---- zero init (ws is poisoned 0xAA before every call) ----
  hipMemsetAsync(hist, 0, (size_t)NN*NR*50*sizeof(int), stream);
  hipMemsetAsync(cnt,  0, (size_t)NN*NR*sizeof(int), stream);
  hipMemsetAsync(chan, 0, (size_t)2*HD*sizeof(float), stream);
  hipMemsetAsync(gmaxk,0, (size_t)NBATCH*sizeof(unsigned), stream);
  hipMemsetAsync(denom,0, (size_t)NBATCH*sizeof(float), stream);
  hipMemsetAsync(pooled,0,(size_t)NBATCH*HD*sizeof(float), stream);

  // ---- folded weights ----
  k_weff<<<NR*50, HD, 0, stream>>>(emb0,emb1,emb2,emb3,emb4,emb5, W1, 384*HD, W1eff);
  k_weff<<<50,    HD, 0, stream>>>(emb0,emb1,emb2,emb3,emb4,emb5, root1, 0, R1eff);

  // ---- histograms + counts ----
  k_hist<<<(NE+255)/256, 256, 0, stream>>>(ei, et, x, hist, cnt);
  k_invc<<<(NN*NR+255)/256, 256, 0, stream>>>(cnt, invc);

  // ---- layer 1 ----
  k_layer1<<<NN, HD, 0, stream>>>(x, hist, invc, W1eff, R1eff, b1, h1);

  // ---- layer 2: root term, then per-relation mean @ W2_r ----
  dim3 ggrid(4, (NN+63)/64);
  k_gemm<<<ggrid, 256, 0, stream>>>(h1, root2, hC, NN, HD, nullptr, 0, 0, b2, 0);
  for (int r=0; r<NR; r++){
    hipMemsetAsync(hS, 0, N256, stream);
    k_scatter<<<(NE+3)/4, 256, 0, stream>>>(ei, et, h1, hS, r);
    k_gemm<<<ggrid, 256, 0, stream>>>(hS, W2 + (size_t)r*HD*HD, hC, NN, HD,
                                      invc, NR, r, nullptr, 1);
  }
  k_sigmoid<<<((NN*HD/4)+255)/256, 256, 0, stream>>>(hC, NN*HD/4);   // hC = h2

  // ---- gate linear (g into h1's space), BN stats ----
  k_gemm<<<ggrid, 256, 0, stream>>>(hC, g1w, h1, NN, HD, nullptr, 0, 0, g1b, 0);
  k_bnstats<<<(NN+127)/128, HD, 0, stream>>>(h1, chan);
  k_bnfin<<<1, HD, 0, stream>>>(chan, bng, bnb, bnp);

  // ---- gate scalar + segment softmax + pooling ----
  k_gate<<<(NN+3)/4, 256, 0, stream>>>(h1, bnp, g2w, g2b, batch, gate, gmaxk);
  k_exp<<<(NN+255)/256, 256, 0, stream>>>(gate, gmaxk, batch, expv, denom);
  k_pool<<<(NN+3)/4, 256, 0, stream>>>(hC, expv, denom, batch, pooled);
  k_out<<<(NBATCH+3)/4, 256, 0, stream>>>(pooled, glw, glb, out);
}

// Round 5
// 1831.239 us; speedup vs baseline: 1.8228x; 1.8228x over previous
//
#include <hip/hip_runtime.h>
#include <hip/hip_bf16.h>
#include <cstdint>

#define NN 50000      // nodes
#define NE 500000     // edges
#define NR 4          // relations
#define NBATCH 512    // graphs
#define HD 256        // hidden/out width
#define NSEG (NN*NR)  // 200000 (dst,rel) segments
#define CHUNK 10000   // nodes per agg/gemm chunk (agg buf = 41 MB)

__constant__ int c_off[6] = {0,33,38,41,45,47};   // cumulative CARD offsets (total 50)

__device__ __forceinline__ float sigf(float x){ return 1.0f/(1.0f+__expf(-x)); }

// ---------- folded weight precompute:  out[rc][h] = emb_j[cl] . W[r, j*64.. , h] ----------
__global__ void k_weff(const float* __restrict__ e0,const float* __restrict__ e1,
                       const float* __restrict__ e2,const float* __restrict__ e3,
                       const float* __restrict__ e4,const float* __restrict__ e5,
                       const float* __restrict__ W, int rstride,
                       float* __restrict__ out){
  int rc = blockIdx.x, h = threadIdx.x;
  int r = rc/50, cg = rc%50;
  int j, cl;
  if      (cg>=47){j=5;cl=cg-47;} else if (cg>=45){j=4;cl=cg-45;}
  else if (cg>=41){j=3;cl=cg-41;} else if (cg>=38){j=2;cl=cg-38;}
  else if (cg>=33){j=1;cl=cg-33;} else            {j=0;cl=cg;}
  const float* emb = j==0?e0:j==1?e1:j==2?e2:j==3?e3:j==4?e4:e5;
  const float* wb = W + (size_t)r*rstride + (size_t)(j*64)*HD + h;
  float acc = 0.f;
  #pragma unroll 8
  for (int k=0;k<64;k++) acc += emb[cl*64+k]*wb[(size_t)k*HD];
  out[(size_t)rc*HD+h] = acc;
}

// ---------- per-(dst,rel) histogram of source categorical features + segment counts ----------
__global__ void k_hist(const int* __restrict__ ei, const int* __restrict__ et,
                       const int* __restrict__ x, int* __restrict__ hist,
                       int* __restrict__ cnt){
  int e = blockIdx.x*256 + threadIdx.x;
  if (e >= NE) return;
  int s = ei[e], d = ei[NE+e], t = et[e];
  int seg = d*NR + t;
  atomicAdd(&cnt[seg], 1);
  int base = seg*50;
  #pragma unroll
  for (int j=0;j<6;j++){
    int c = x[s*6+j];
    atomicAdd(&hist[base + c_off[j] + c], 1);
  }
}

__global__ void k_invc(const int* __restrict__ cnt, float* __restrict__ invc){
  int i = blockIdx.x*256 + threadIdx.x;
  if (i >= NSEG) return;
  invc[i] = 1.0f / fmaxf((float)cnt[i], 1.0f);
}

// ---------- layer 1: h1 = sigmoid( b1 + root-lookups + sum_r (hist/cnt) @ W1eff ) ----------
__global__ void k_layer1(const int* __restrict__ x, const int* __restrict__ hist,
                         const float* __restrict__ invc, const float* __restrict__ W1eff,
                         const float* __restrict__ R1eff, const float* __restrict__ b1,
                         float* __restrict__ h1){
  __shared__ int sh[200];
  __shared__ float siv[4];
  int n = blockIdx.x, tid = threadIdx.x;
  if (tid < 200) sh[tid] = hist[(size_t)n*200 + tid];
  if (tid >= 200 && tid < 204) siv[tid-200] = invc[n*4 + tid - 200];
  __syncthreads();
  float acc = b1[tid];
  #pragma unroll
  for (int j=0;j<6;j++){
    int cg = c_off[j] + x[n*6+j];
    acc += R1eff[(size_t)cg*HD + tid];
  }
  for (int r=0;r<4;r++){
    float iv = siv[r];
    for (int c=0;c<50;c++){
      int w = sh[r*50+c];
      if (w) acc += ((float)w*iv) * W1eff[(size_t)(r*50+c)*HD + tid];
    }
  }
  h1[(size_t)n*HD + tid] = sigf(acc);
}

// ---------- 3-kernel exclusive prefix scan over cnt[NSEG] ----------
#define SC_T 256
#define SC_NB ((NSEG/4 + SC_T - 1)/SC_T)   // 196 blocks, 4 elems/thread via int4

__global__ void k_scan1(const int* __restrict__ cnt, int* __restrict__ bsum){
  __shared__ int sh[SC_T];
  int b = blockIdx.x, t = threadIdx.x;
  int i4 = b*SC_T + t;
  int s = 0;
  if (i4 < NSEG/4){ int4 v = ((const int4*)cnt)[i4]; s = v.x+v.y+v.z+v.w; }
  sh[t] = s; __syncthreads();
  for (int o=128;o>0;o>>=1){ if (t<o) sh[t]+=sh[t+o]; __syncthreads(); }
  if (t==0) bsum[b] = sh[0];
}

__global__ void k_scan2(const int* __restrict__ bsum, int* __restrict__ boff,
                        int* __restrict__ offs){
  __shared__ int sh[256];
  int t = threadIdx.x;
  int v = (t < SC_NB) ? bsum[t] : 0;
  sh[t] = v; __syncthreads();
  for (int o=1;o<256;o<<=1){
    int add = (t>=o) ? sh[t-o] : 0; __syncthreads();
    sh[t] += add; __syncthreads();
  }
  if (t < SC_NB) boff[t] = sh[t] - v;   // exclusive block offset
  if (t == 255) offs[NSEG] = sh[255];   // total (= NE)
}

__global__ void k_scan3(const int* __restrict__ cnt, const int* __restrict__ boff,
                        int* __restrict__ offs, int* __restrict__ cursor){
  __shared__ int sh[SC_T];
  int b = blockIdx.x, t = threadIdx.x;
  int i4 = b*SC_T + t;
  int4 v = {0,0,0,0};
  if (i4 < NSEG/4) v = ((const int4*)cnt)[i4];
  int s = v.x+v.y+v.z+v.w;
  sh[t] = s; __syncthreads();
  for (int o=1;o<256;o<<=1){
    int add = (t>=o) ? sh[t-o] : 0; __syncthreads();
    sh[t] += add; __syncthreads();
  }
  if (i4 < NSEG/4){
    int excl = sh[t] - s + boff[b];
    int4 ov; ov.x = excl; ov.y = ov.x+v.x; ov.z = ov.y+v.y; ov.w = ov.z+v.z;
    ((int4*)offs)[i4] = ov; ((int4*)cursor)[i4] = ov;
  }
}

// ---------- bin edges into CSR slots by (dst,rel) ----------
__global__ void k_bin(const int* __restrict__ ei, const int* __restrict__ et,
                      int* __restrict__ cursor, int* __restrict__ esrc){
  int e = blockIdx.x*256 + threadIdx.x;
  if (e >= NE) return;
  int s = ei[e], d = ei[NE+e], t = et[e];
  int slot = atomicAdd(&cursor[d*NR + t], 1);
  esrc[slot] = s;
}

// ---------- gather-aggregate for a node chunk:
//            agg[n][r*256+c] = mean_{e in seg(base+n,r)} h1[src_e][c] ----------
__global__ void k_agg(const int* __restrict__ offs, const int* __restrict__ esrc,
                      const float* __restrict__ h1, float* __restrict__ agg,
                      int base, int m){
  int gid = blockIdx.x*256 + threadIdx.x;
  int n = gid >> 6;          // one wave per node
  if (n >= m) return;
  int lane = gid & 63;
  int gn = base + n;
  #pragma unroll
  for (int r=0;r<NR;r++){
    int a = offs[gn*NR+r], b = offs[gn*NR+r+1];
    float4 acc = {0.f,0.f,0.f,0.f};
    for (int e=a;e<b;e++){
      int s = esrc[e];
      float4 v = *(const float4*)(h1 + (size_t)s*HD + lane*4);
      acc.x+=v.x; acc.y+=v.y; acc.z+=v.z; acc.w+=v.w;
    }
    float iv = 1.0f / (float)max(b-a, 1);
    acc.x*=iv; acc.y*=iv; acc.z*=iv; acc.w*=iv;
    *(float4*)(agg + (size_t)n*(NR*HD) + r*HD + lane*4) = acc;
  }
}

// ---------- fp32 tiled GEMM: C[M,256] (=/+)= A[M,K] @ B[K,256] (+bias) (+sigmoid) ----------
__global__ __launch_bounds__(256) void k_gemm(
    const float* __restrict__ A, const float* __restrict__ B, float* __restrict__ C,
    int M, int K, const float* __restrict__ bias, int acc_flag, int act_sig){
  __shared__ float As[16][68];   // [k][m]
  __shared__ float Bs[16][68];   // [k][n]
  int bm = blockIdx.y*64, bn = blockIdx.x*64;
  int tid = threadIdx.x;
  int tx = tid & 15, ty = tid >> 4;
  float acc[4][4] = {};
  int lm = tid >> 2;           // A row within tile
  int lk = (tid & 3) * 4;      // A k within tile
  int brow = tid >> 4;         // B k row
  int bcol = (tid & 15) * 4;   // B col
  for (int k0 = 0; k0 < K; k0 += 16){
    int arow = bm + lm; if (arow >= M) arow = M-1;
    float4 av = *(const float4*)(A + (size_t)arow*K + k0 + lk);
    As[lk+0][lm]=av.x; As[lk+1][lm]=av.y; As[lk+2][lm]=av.z; As[lk+3][lm]=av.w;
    float4 bv = *(const float4*)(B + (size_t)(k0+brow)*HD + bn + bcol);
    *(float4*)&Bs[brow][bcol] = bv;
    __syncthreads();
    #pragma unroll
    for (int kk=0;kk<16;kk++){
      float4 a4 = *(const float4*)&As[kk][ty*4];
      float4 b4 = *(const float4*)&Bs[kk][tx*4];
      acc[0][0]+=a4.x*b4.x; acc[0][1]+=a4.x*b4.y; acc[0][2]+=a4.x*b4.z; acc[0][3]+=a4.x*b4.w;
      acc[1][0]+=a4.y*b4.x; acc[1][1]+=a4.y*b4.y; acc[1][2]+=a4.y*b4.z; acc[1][3]+=a4.y*b4.w;
      acc[2][0]+=a4.z*b4.x; acc[2][1]+=a4.z*b4.y; acc[2][2]+=a4.z*b4.z; acc[2][3]+=a4.z*b4.w;
      acc[3][0]+=a4.w*b4.x; acc[3][1]+=a4.w*b4.y; acc[3][2]+=a4.w*b4.z; acc[3][3]+=a4.w*b4.w;
    }
    __syncthreads();
  }
  for (int i=0;i<4;i++){
    int row = bm + ty*4 + i;
    if (row >= M) continue;
    #pragma unroll
    for (int j=0;j<4;j++){
      int col = bn + tx*4 + j;
      float v = acc[i][j];
      if (bias) v += bias[col];
      float* cp = &C[(size_t)row*HD + col];
      if (acc_flag) v += *cp;
      if (act_sig) v = sigf(v);
      *cp = v;
    }
  }
}

// ---------- BN stats (training-mode, biased var) ----------
__global__ void k_bnstats(const float* __restrict__ g, float* __restrict__ chan){
  int c = threadIdx.x;
  int r0 = blockIdx.x*128;
  int rend = min(r0+128, NN);
  float s=0.f, q=0.f;
  for (int row=r0; row<rend; row++){
    float v = g[(size_t)row*HD + c];
    s += v; q += v*v;
  }
  atomicAdd(&chan[c], s); atomicAdd(&chan[HD+c], q);
}

__global__ void k_bnfin(const float* __restrict__ chan, const float* __restrict__ bng,
                        const float* __restrict__ bnb, float* __restrict__ bnp){
  int c = threadIdx.x;
  float mu = chan[c]/(float)NN;
  float var = chan[HD+c]/(float)NN - mu*mu;
  float scale = bng[c]*rsqrtf(var + 1e-5f);
  bnp[c] = bnb[c] - mu*scale;     // shift
  bnp[HD+c] = scale;              // scale
}

__device__ __forceinline__ unsigned fenc(float f){
  unsigned u = __float_as_uint(f);
  return (u & 0x80000000u) ? ~u : (u | 0x80000000u);
}
__device__ __forceinline__ float fdec(unsigned k){
  return (k & 0x80000000u) ? __uint_as_float(k & 0x7fffffffu) : __uint_as_float(~k);
}

// ---------- gate = relu(BN(g)) . g2_w + g2_b ; atomic segment max ----------
__global__ void k_gate(const float* __restrict__ g, const float* __restrict__ bnp,
                       const float* __restrict__ g2w, const float* __restrict__ g2b,
                       const int* __restrict__ batch, float* __restrict__ gate,
                       unsigned* __restrict__ gmaxk){
  int lane = threadIdx.x & 63;
  int n = blockIdx.x*4 + (threadIdx.x>>6);
  if (n >= NN) return;
  float s = 0.f;
  #pragma unroll
  for (int k=0;k<4;k++){
    int c = lane + k*64;
    float v = g[(size_t)n*HD + c]*bnp[HD+c] + bnp[c];
    v = fmaxf(v, 0.f);
    s += v * g2w[c];
  }
  #pragma unroll
  for (int o=32;o>0;o>>=1) s += __shfl_down(s, o);
  if (lane==0){
    float gt = s + g2b[0];
    gate[n] = gt;
    atomicMax(&gmaxk[batch[n]], fenc(gt));
  }
}

__global__ void k_exp(const float* __restrict__ gate, const unsigned* __restrict__ gmaxk,
                      const int* __restrict__ batch, float* __restrict__ expv,
                      float* __restrict__ denom){
  int n = blockIdx.x*256 + threadIdx.x;
  if (n >= NN) return;
  int b = batch[n];
  float e = __expf(gate[n] - fdec(gmaxk[b]));
  expv[n] = e;
  atomicAdd(&denom[b], e);
}

__global__ void k_pool(const float* __restrict__ h2, const float* __restrict__ expv,
                       const float* __restrict__ denom, const int* __restrict__ batch,
                       float* __restrict__ pooled){
  int lane = threadIdx.x & 63;
  int n = blockIdx.x*4 + (threadIdx.x>>6);
  if (n >= NN) return;
  int b = batch[n];
  float w = expv[n] / (denom[b] + 1e-16f);
  float4 v = *(const float4*)(h2 + (size_t)n*HD + lane*4);
  float* dst = pooled + (size_t)b*HD + lane*4;
  atomicAdd(dst+0, w*v.x); atomicAdd(dst+1, w*v.y);
  atomicAdd(dst+2, w*v.z); atomicAdd(dst+3, w*v.w);
}

__global__ void k_out(const float* __restrict__ pooled, const float* __restrict__ glw,
                      const float* __restrict__ glb, float* __restrict__ out){
  int lane = threadIdx.x & 63;
  int b = blockIdx.x*4 + (threadIdx.x>>6);
  if (b >= NBATCH) return;
  float s = 0.f;
  #pragma unroll
  for (int k=0;k<4;k++){
    int c = lane + k*64;
    s += pooled[(size_t)b*HD + c]*glw[c];
  }
  #pragma unroll
  for (int o=32;o>0;o>>=1) s += __shfl_down(s, o);
  if (lane==0) out[b] = sigf(s + glb[0]);
}

extern "C" void kernel_launch(void* const* d_in, const int* in_sizes, int n_in,
                              void* d_out, int out_size, void* d_ws, size_t ws_size,
                              hipStream_t stream) {
  const int* x     = (const int*)d_in[0];
  const int* ei    = (const int*)d_in[1];
  const int* et    = (const int*)d_in[2];
  const int* batch = (const int*)d_in[3];
  const float* emb0 = (const float*)d_in[4];
  const float* emb1 = (const float*)d_in[5];
  const float* emb2 = (const float*)d_in[6];
  const float* emb3 = (const float*)d_in[7];
  const float* emb4 = (const float*)d_in[8];
  const float* emb5 = (const float*)d_in[9];
  const float* W1    = (const float*)d_in[10];
  const float* root1 = (const float*)d_in[11];
  const float* b1    = (const float*)d_in[12];
  const float* W2    = (const float*)d_in[13];  // [R,H,O] flat == [1024,256]
  const float* root2 = (const float*)d_in[14];
  const float* b2    = (const float*)d_in[15];
  const float* g1w   = (const float*)d_in[16];
  const float* g1b   = (const float*)d_in[17];
  const float* bng   = (const float*)d_in[18];
  const float* bnb   = (const float*)d_in[19];
  const float* g2w   = (const float*)d_in[20];
  const float* g2b   = (const float*)d_in[21];
  const float* glw   = (const float*)d_in[22];
  const float* glb   = (const float*)d_in[23];
  float* out = (float*)d_out;

  // ---- workspace carve-up (256B aligned), total ≈150 MB ----
  char* w = (char*)d_ws;
  auto alloc = [&](size_t bytes)->char* {
    char* p = w; w += (bytes + 255) & ~(size_t)255; return p;
  };
  const size_t N256 = (size_t)NN*HD*sizeof(float);            // 51.2 MB
  float* h1   = (float*)alloc(N256);                          // layer1 out; later g
  float* hC   = (float*)alloc(N256);                          // h2 accumulator / h2
  float* agg  = (float*)alloc((size_t)CHUNK*NR*HD*sizeof(float)); // 41 MB; hist(40MB) aliased
  int*   hist = (int*)agg;                                    // used before agg is written
  int*   cnt  = (int*)alloc((size_t)NSEG*sizeof(int));
  float* invc = (float*)alloc((size_t)NSEG*sizeof(float));
  int*   offs = (int*)alloc((size_t)(NSEG+1)*sizeof(int));
  int*   cursor=(int*)alloc((size_t)NSEG*sizeof(int));
  int*   bsum = (int*)alloc((size_t)SC_NB*sizeof(int));
  int*   boff = (int*)alloc((size_t)SC_NB*sizeof(int));
  int*   esrc = (int*)alloc((size_t)NE*sizeof(int));
  float* W1eff= (float*)alloc((size_t)NR*50*HD*sizeof(float));
  float* R1eff= (float*)alloc((size_t)50*HD*sizeof(float));
  float* gate = (float*)alloc((size_t)NN*sizeof(float));
  float* expv = (float*)alloc((size_t)NN*sizeof(float));
  float* chan = (float*)alloc((size_t)2*HD*sizeof(float));
  float* bnp  = (float*)alloc((size_t)2*HD*sizeof(float));
  unsigned* gmaxk = (unsigned*)alloc((size_t)NBATCH*sizeof(unsigned));
  float* denom    = (float*)alloc((size_t)NBATCH*sizeof(float));
  float* pooled   = (float*)alloc((size_t)NBATCH*HD*sizeof(float));

  // ---- zero init (ws is poisoned 0xAA before every call) ----
  hipMemsetAsync(hist, 0, (size_t)NSEG*50*sizeof(int), stream);
  hipMemsetAsync(cnt,  0, (size_t)NSEG*sizeof(int), stream);
  hipMemsetAsync(chan, 0, (size_t)2*HD*sizeof(float), stream);
  hipMemsetAsync(gmaxk,0, (size_t)NBATCH*sizeof(unsigned), stream);
  hipMemsetAsync(denom,0, (size_t)NBATCH*sizeof(float), stream);
  hipMemsetAsync(pooled,0,(size_t)NBATCH*HD*sizeof(float), stream);

  // ---- folded weights ----
  k_weff<<<NR*50, HD, 0, stream>>>(emb0,emb1,emb2,emb3,emb4,emb5, W1, 384*HD, W1eff);
  k_weff<<<50,    HD, 0, stream>>>(emb0,emb1,emb2,emb3,emb4,emb5, root1, 0, R1eff);

  // ---- histograms + counts ----
  k_hist<<<(NE+255)/256, 256, 0, stream>>>(ei, et, x, hist, cnt);
  k_invc<<<(NSEG+255)/256, 256, 0, stream>>>(cnt, invc);

  // ---- layer 1 (consumes hist before agg overwrites it) ----
  k_layer1<<<NN, HD, 0, stream>>>(x, hist, invc, W1eff, R1eff, b1, h1);

  // ---- CSR build: scan + bin ----
  k_scan1<<<SC_NB, SC_T, 0, stream>>>(cnt, bsum);
  k_scan2<<<1, 256, 0, stream>>>(bsum, boff, offs);
  k_scan3<<<SC_NB, SC_T, 0, stream>>>(cnt, boff, offs, cursor);
  k_bin<<<(NE+255)/256, 256, 0, stream>>>(ei, et, cursor, esrc);

  // ---- layer 2: root GEMM over all nodes, then chunked agg + K=1024 GEMM (+sigmoid) ----
  dim3 ggrid(4, (NN+63)/64);
  k_gemm<<<ggrid, 256, 0, stream>>>(h1, root2, hC, NN, HD, b2, 0, 0);
  for (int c0 = 0; c0 < NN; c0 += CHUNK){
    int m = min(CHUNK, NN - c0);
    k_agg<<<(m*64+255)/256, 256, 0, stream>>>(offs, esrc, h1, agg, c0, m);
    dim3 cg(4, (m+63)/64);
    k_gemm<<<cg, 256, 0, stream>>>(agg, W2, hC + (size_t)c0*HD, m, NR*HD, nullptr, 1, 1);
  }
  // hC = h2 now

  // ---- gate linear (g into h1's space), BN stats ----
  k_gemm<<<ggrid, 256, 0, stream>>>(hC, g1w, h1, NN, HD, g1b, 0, 0);
  k_bnstats<<<(NN+127)/128, HD, 0, stream>>>(h1, chan);
  k_bnfin<<<1, HD, 0, stream>>>(chan, bng, bnb, bnp);

  // ---- gate scalar + segment softmax + pooling ----
  k_gate<<<(NN+3)/4, 256, 0, stream>>>(h1, bnp, g2w, g2b, batch, gate, gmaxk);
  k_exp<<<(NN+255)/256, 256, 0, stream>>>(gate, gmaxk, batch, expv, denom);
  k_pool<<<(NN+3)/4, 256, 0, stream>>>(hC, expv, denom, batch, pooled);
  k_out<<<(NBATCH+3)/4, 256, 0, stream>>>(pooled, glw, glb, out);
}

// Round 7
// 1207.308 us; speedup vs baseline: 2.7648x; 1.5168x over previous
//
#include <hip/hip_runtime.h>
#include <hip/hip_bf16.h>
#include <cstdint>

#define NN 50000      // nodes
#define NE 500000     // edges
#define NR 4          // relations
#define NBATCH 512    // graphs
#define HD 256        // hidden/out width
#define NSEG (NN*NR)  // 200000 (dst,rel) segments
#define CHUNK 10000   // nodes per agg/gemm chunk

__constant__ int c_off[6] = {0,33,38,41,45,47};   // cumulative CARD offsets (total 50)

__device__ __forceinline__ float sigf(float x){ return 1.0f/(1.0f+__expf(-x)); }
__device__ __forceinline__ float bf2f(unsigned short b){ return __uint_as_float((unsigned)b<<16); }
__device__ __forceinline__ unsigned short f2bf(float f){
  unsigned u = __float_as_uint(f);
  return (unsigned short)((u + 0x7fffu + ((u>>16)&1u)) >> 16);   // RNE
}

typedef short bf16raw8 __attribute__((ext_vector_type(8)));
typedef float f32x4v  __attribute__((ext_vector_type(4)));
union LD16 { uint4 u; bf16raw8 v; };

// ---------- folded weight precompute (fp32):  out[rc][h] = emb_j[cl] . W[r, j*64.. , h] ----------
__global__ void k_weff(const float* __restrict__ e0,const float* __restrict__ e1,
                       const float* __restrict__ e2,const float* __restrict__ e3,
                       const float* __restrict__ e4,const float* __restrict__ e5,
                       const float* __restrict__ W, int rstride,
                       float* __restrict__ out){
  int rc = blockIdx.x, h = threadIdx.x;
  int r = rc/50, cg = rc%50;
  int j, cl;
  if      (cg>=47){j=5;cl=cg-47;} else if (cg>=45){j=4;cl=cg-45;}
  else if (cg>=41){j=3;cl=cg-41;} else if (cg>=38){j=2;cl=cg-38;}
  else if (cg>=33){j=1;cl=cg-33;} else            {j=0;cl=cg;}
  const float* emb = j==0?e0:j==1?e1:j==2?e2:j==3?e3:j==4?e4:e5;
  const float* wb = W + (size_t)r*rstride + (size_t)(j*64)*HD + h;
  float acc = 0.f;
  #pragma unroll 8
  for (int k=0;k<64;k++) acc += emb[cl*64+k]*wb[(size_t)k*HD];
  out[(size_t)rc*HD+h] = acc;
}

// ---------- per-(dst,rel) histogram + segment counts ----------
__global__ void k_hist(const int* __restrict__ ei, const int* __restrict__ et,
                       const int* __restrict__ x, int* __restrict__ hist,
                       int* __restrict__ cnt){
  int e = blockIdx.x*256 + threadIdx.x;
  if (e >= NE) return;
  int s = ei[e], d = ei[NE+e], t = et[e];
  int seg = d*NR + t;
  atomicAdd(&cnt[seg], 1);
  int base = seg*50;
  #pragma unroll
  for (int j=0;j<6;j++){
    int c = x[s*6+j];
    atomicAdd(&hist[base + c_off[j] + c], 1);
  }
}

__global__ void k_invc(const int* __restrict__ cnt, float* __restrict__ invc){
  int i = blockIdx.x*256 + threadIdx.x;
  if (i >= NSEG) return;
  invc[i] = 1.0f / fmaxf((float)cnt[i], 1.0f);
}

// ---------- A1[n][256] bf16 = [200 hist-mean | 50 root one-hot | 6 zero] ----------
__global__ void k_buildA(const int* __restrict__ x, const int* __restrict__ hist,
                         const float* __restrict__ invc, unsigned short* __restrict__ A1){
  int n = blockIdx.x, tid = threadIdx.x;
  float v = 0.f;
  if (tid < 200){
    v = (float)hist[(size_t)n*200 + tid] * invc[n*4 + (tid/50)];
  } else if (tid < 250){
    int cg = tid - 200;
    #pragma unroll
    for (int j=0;j<6;j++) if (cg == c_off[j] + x[n*6+j]) v = 1.f;
  }
  A1[(size_t)n*256 + tid] = f2bf(v);
}

// ---------- B1t[o][k] bf16 from W1eff(200 rows)+R1eff(50 rows), zero-padded to 256 ----------
__global__ void k_b1t(const float* __restrict__ W1eff, const float* __restrict__ R1eff,
                      unsigned short* __restrict__ B1t){
  int id = blockIdx.x*256 + threadIdx.x;      // 256*256 total
  int k = id & 255, o = id >> 8;
  float v = 0.f;
  if (k < 200) v = W1eff[(size_t)k*HD + o];
  else if (k < 250) v = R1eff[(size_t)(k-200)*HD + o];
  B1t[(size_t)o*256 + k] = f2bf(v);
}

// ---------- transpose+convert fp32 W[K][O] -> bf16 Wt[O][K] ----------
__global__ void k_tconv(const float* __restrict__ W, unsigned short* __restrict__ Wt,
                        int K, int O){
  int id = blockIdx.x*256 + threadIdx.x;
  if (id >= K*O) return;
  int k = id % K, o = id / K;
  Wt[(size_t)o*K + k] = f2bf(W[(size_t)k*O + o]);
}

// ---------- 3-kernel exclusive prefix scan over cnt[NSEG] ----------
#define SC_T 256
#define SC_NB ((NSEG/4 + SC_T - 1)/SC_T)   // 196 blocks

__global__ void k_scan1(const int* __restrict__ cnt, int* __restrict__ bsum){
  __shared__ int sh[SC_T];
  int b = blockIdx.x, t = threadIdx.x;
  int i4 = b*SC_T + t;
  int s = 0;
  if (i4 < NSEG/4){ int4 v = ((const int4*)cnt)[i4]; s = v.x+v.y+v.z+v.w; }
  sh[t] = s; __syncthreads();
  for (int o=128;o>0;o>>=1){ if (t<o) sh[t]+=sh[t+o]; __syncthreads(); }
  if (t==0) bsum[b] = sh[0];
}

__global__ void k_scan2(const int* __restrict__ bsum, int* __restrict__ boff,
                        int* __restrict__ offs){
  __shared__ int sh[256];
  int t = threadIdx.x;
  int v = (t < SC_NB) ? bsum[t] : 0;
  sh[t] = v; __syncthreads();
  for (int o=1;o<256;o<<=1){
    int add = (t>=o) ? sh[t-o] : 0; __syncthreads();
    sh[t] += add; __syncthreads();
  }
  if (t < SC_NB) boff[t] = sh[t] - v;
  if (t == 255) offs[NSEG] = sh[255];
}

__global__ void k_scan3(const int* __restrict__ cnt, const int* __restrict__ boff,
                        int* __restrict__ offs, int* __restrict__ cursor){
  __shared__ int sh[SC_T];
  int b = blockIdx.x, t = threadIdx.x;
  int i4 = b*SC_T + t;
  int4 v = {0,0,0,0};
  if (i4 < NSEG/4) v = ((const int4*)cnt)[i4];
  int s = v.x+v.y+v.z+v.w;
  sh[t] = s; __syncthreads();
  for (int o=1;o<256;o<<=1){
    int add = (t>=o) ? sh[t-o] : 0; __syncthreads();
    sh[t] += add; __syncthreads();
  }
  if (i4 < NSEG/4){
    int excl = sh[t] - s + boff[b];
    int4 ov; ov.x = excl; ov.y = ov.x+v.x; ov.z = ov.y+v.y; ov.w = ov.z+v.z;
    ((int4*)offs)[i4] = ov; ((int4*)cursor)[i4] = ov;
  }
}

// ---------- bin edges into CSR slots by (dst,rel) ----------
__global__ void k_bin(const int* __restrict__ ei, const int* __restrict__ et,
                      int* __restrict__ cursor, int* __restrict__ esrc){
  int e = blockIdx.x*256 + threadIdx.x;
  if (e >= NE) return;
  int s = ei[e], d = ei[NE+e], t = et[e];
  int slot = atomicAdd(&cursor[d*NR + t], 1);
  esrc[slot] = s;
}

// ---------- gather-aggregate (bf16 in/out, fp32 accum) ----------
__global__ void k_agg(const int* __restrict__ offs, const int* __restrict__ esrc,
                      const unsigned short* __restrict__ h1, unsigned short* __restrict__ agg,
                      int base, int m){
  int gid = blockIdx.x*256 + threadIdx.x;
  int n = gid >> 6;          // one wave per node
  if (n >= m) return;
  int lane = gid & 63;
  int gn = base + n;
  #pragma unroll
  for (int r=0;r<NR;r++){
    int a = offs[gn*NR+r], b = offs[gn*NR+r+1];
    float a0=0.f,a1=0.f,a2=0.f,a3=0.f;
    for (int e=a;e<b;e++){
      int s = esrc[e];
      ushort4 v = *(const ushort4*)(h1 + (size_t)s*HD + lane*4);
      a0+=bf2f(v.x); a1+=bf2f(v.y); a2+=bf2f(v.z); a3+=bf2f(v.w);
    }
    float iv = 1.0f / (float)max(b-a, 1);
    ushort4 o;
    o.x=f2bf(a0*iv); o.y=f2bf(a1*iv); o.z=f2bf(a2*iv); o.w=f2bf(a3*iv);
    *(ushort4*)(agg + (size_t)n*(NR*HD) + r*HD + lane*4) = o;
  }
}

// ---------- bf16 MFMA GEMM, no LDS: C[M,256] = A[M,K] @ Bt[256,K]^T (+bias)(+Cin)(+sigmoid) ----------
// block = 256 thr = 4 waves (2x2), block tile 128x128, wave tile 64x64 (4x4 frags 16x16x32)
__global__ __launch_bounds__(256) void k_mfma(
    const unsigned short* __restrict__ A,    // [M][K] bf16
    const unsigned short* __restrict__ Bt,   // [256][K] bf16 (pre-transposed)
    const float* __restrict__ bias,          // [256] or null
    const unsigned short* __restrict__ Cin,  // [M][256] bf16 or null (added)
    unsigned short* __restrict__ outB,       // [M][256] bf16 or null
    float* __restrict__ outF,                // [M][256] f32 or null
    int M, int K, int actsig){
  int tid = threadIdx.x;
  int wave = tid >> 6, lane = tid & 63;
  int wm = (wave >> 1) * 64, wn = (wave & 1) * 64;
  int bm = blockIdx.y * 128, bn = blockIdx.x * 128;
  int lrow = lane & 15, lk8 = (lane >> 4) * 8;

  f32x4v acc[4][4] = {};
  for (int k0 = 0; k0 < K; k0 += 32){
    bf16raw8 aF[4], bF[4];
    #pragma unroll
    for (int mi = 0; mi < 4; mi++){
      int row = bm + wm + mi*16 + lrow; if (row > M-1) row = M-1;
      LD16 t; t.u = *(const uint4*)(A + (size_t)row*K + k0 + lk8); aF[mi] = t.v;
    }
    #pragma unroll
    for (int nj = 0; nj < 4; nj++){
      int col = bn + wn + nj*16 + lrow;   // always < 256
      LD16 t; t.u = *(const uint4*)(Bt + (size_t)col*K + k0 + lk8); bF[nj] = t.v;
    }
    #pragma unroll
    for (int mi = 0; mi < 4; mi++)
      #pragma unroll
      for (int nj = 0; nj < 4; nj++)
        acc[mi][nj] = __builtin_amdgcn_mfma_f32_16x16x32_bf16(aF[mi], bF[nj], acc[mi][nj], 0, 0, 0);
  }
  int r0 = (lane >> 4) * 4;
  #pragma unroll
  for (int mi = 0; mi < 4; mi++){
    #pragma unroll
    for (int i = 0; i < 4; i++){
      int row = bm + wm + mi*16 + r0 + i;
      if (row >= M) continue;
      #pragma unroll
      for (int nj = 0; nj < 4; nj++){
        int col = bn + wn + nj*16 + lrow;
        float v = acc[mi][nj][i];
        if (bias) v += bias[col];
        if (Cin)  v += bf2f(Cin[(size_t)row*HD + col]);
        if (actsig) v = sigf(v);
        if (outB) outB[(size_t)row*HD + col] = f2bf(v);
        if (outF) outF[(size_t)row*HD + col] = v;
      }
    }
  }
}

// ---------- BN stats (training-mode, biased var) ----------
__global__ void k_bnstats(const float* __restrict__ g, float* __restrict__ chan){
  int c = threadIdx.x;
  int r0 = blockIdx.x*128;
  int rend = min(r0+128, NN);
  float s=0.f, q=0.f;
  for (int row=r0; row<rend; row++){
    float v = g[(size_t)row*HD + c];
    s += v; q += v*v;
  }
  atomicAdd(&chan[c], s); atomicAdd(&chan[HD+c], q);
}

__global__ void k_bnfin(const float* __restrict__ chan, const float* __restrict__ bng,
                        const float* __restrict__ bnb, float* __restrict__ bnp){
  int c = threadIdx.x;
  float mu = chan[c]/(float)NN;
  float var = chan[HD+c]/(float)NN - mu*mu;
  float scale = bng[c]*rsqrtf(var + 1e-5f);
  bnp[c] = bnb[c] - mu*scale;     // shift
  bnp[HD+c] = scale;              // scale
}

__device__ __forceinline__ unsigned fenc(float f){
  unsigned u = __float_as_uint(f);
  return (u & 0x80000000u) ? ~u : (u | 0x80000000u);
}
__device__ __forceinline__ float fdec(unsigned k){
  return (k & 0x80000000u) ? __uint_as_float(k & 0x7fffffffu) : __uint_as_float(~k);
}

// ---------- gate = relu(BN(g)) . g2_w + g2_b ; atomic segment max ----------
__global__ void k_gate(const float* __restrict__ g, const float* __restrict__ bnp,
                       const float* __restrict__ g2w, const float* __restrict__ g2b,
                       const int* __restrict__ batch, float* __restrict__ gate,
                       unsigned* __restrict__ gmaxk){
  int lane = threadIdx.x & 63;
  int n = blockIdx.x*4 + (threadIdx.x>>6);
  if (n >= NN) return;
  float s = 0.f;
  #pragma unroll
  for (int k=0;k<4;k++){
    int c = lane + k*64;
    float v = g[(size_t)n*HD + c]*bnp[HD+c] + bnp[c];
    v = fmaxf(v, 0.f);
    s += v * g2w[c];
  }
  #pragma unroll
  for (int o=32;o>0;o>>=1) s += __shfl_down(s, o);
  if (lane==0){
    float gt = s + g2b[0];
    gate[n] = gt;
    atomicMax(&gmaxk[batch[n]], fenc(gt));
  }
}

__global__ void k_exp(const float* __restrict__ gate, const unsigned* __restrict__ gmaxk,
                      const int* __restrict__ batch, float* __restrict__ expv,
                      float* __restrict__ denom){
  int n = blockIdx.x*256 + threadIdx.x;
  if (n >= NN) return;
  int b = batch[n];
  float e = __expf(gate[n] - fdec(gmaxk[b]));
  expv[n] = e;
  atomicAdd(&denom[b], e);
}

// ---------- pooled[b] += attn * h2 (h2 bf16) ----------
__global__ void k_pool(const unsigned short* __restrict__ h2, const float* __restrict__ expv,
                       const float* __restrict__ denom, const int* __restrict__ batch,
                       float* __restrict__ pooled){
  int lane = threadIdx.x & 63;
  int n = blockIdx.x*4 + (threadIdx.x>>6);
  if (n >= NN) return;
  int b = batch[n];
  float w = expv[n] / (denom[b] + 1e-16f);
  ushort4 v = *(const ushort4*)(h2 + (size_t)n*HD + lane*4);
  float* dst = pooled + (size_t)b*HD + lane*4;
  atomicAdd(dst+0, w*bf2f(v.x)); atomicAdd(dst+1, w*bf2f(v.y));
  atomicAdd(dst+2, w*bf2f(v.z)); atomicAdd(dst+3, w*bf2f(v.w));
}

__global__ void k_out(const float* __restrict__ pooled, const float* __restrict__ glw,
                      const float* __restrict__ glb, float* __restrict__ out){
  int lane = threadIdx.x & 63;
  int b = blockIdx.x*4 + (threadIdx.x>>6);
  if (b >= NBATCH) return;
  float s = 0.f;
  #pragma unroll
  for (int k=0;k<4;k++){
    int c = lane + k*64;
    s += pooled[(size_t)b*HD + c]*glw[c];
  }
  #pragma unroll
  for (int o=32;o>0;o>>=1) s += __shfl_down(s, o);
  if (lane==0) out[b] = sigf(s + glb[0]);
}

extern "C" void kernel_launch(void* const* d_in, const int* in_sizes, int n_in,
                              void* d_out, int out_size, void* d_ws, size_t ws_size,
                              hipStream_t stream) {
  const int* x     = (const int*)d_in[0];
  const int* ei    = (const int*)d_in[1];
  const int* et    = (const int*)d_in[2];
  const int* batch = (const int*)d_in[3];
  const float* emb0 = (const float*)d_in[4];
  const float* emb1 = (const float*)d_in[5];
  const float* emb2 = (const float*)d_in[6];
  const float* emb3 = (const float*)d_in[7];
  const float* emb4 = (const float*)d_in[8];
  const float* emb5 = (const float*)d_in[9];
  const float* W1    = (const float*)d_in[10];
  const float* root1 = (const float*)d_in[11];
  const float* b1    = (const float*)d_in[12];
  const float* W2    = (const float*)d_in[13];  // [R,H,O] flat == [1024,256]
  const float* root2 = (const float*)d_in[14];
  const float* b2    = (const float*)d_in[15];
  const float* g1w   = (const float*)d_in[16];
  const float* g1b   = (const float*)d_in[17];
  const float* bng   = (const float*)d_in[18];
  const float* bnb   = (const float*)d_in[19];
  const float* g2w   = (const float*)d_in[20];
  const float* g2b   = (const float*)d_in[21];
  const float* glw   = (const float*)d_in[22];
  const float* glb   = (const float*)d_in[23];
  float* out = (float*)d_out;

  // ---- workspace carve-up (256B aligned), total ≈ 150 MB ----
  char* w = (char*)d_ws;
  auto alloc = [&](size_t bytes)->char* {
    char* p = w; w += (bytes + 255) & ~(size_t)255; return p;
  };
  // hist(40MB int) region, later reused as agg(20.5MB bf16)
  char* histReg = alloc((size_t)NSEG*50*sizeof(int));
  int*  hist = (int*)histReg;
  unsigned short* agg = (unsigned short*)histReg;
  // A1(25.6MB bf16) / g(51.2MB f32) union
  char* gReg = alloc((size_t)NN*HD*sizeof(float));
  unsigned short* A1 = (unsigned short*)gReg;
  float* g = (float*)gReg;
  unsigned short* h1   = (unsigned short*)alloc((size_t)NN*HD*2);  // 25.6 MB
  unsigned short* hRes = (unsigned short*)alloc((size_t)NN*HD*2);  // 25.6 MB (root2 -> h2 in place)
  int*   cnt  = (int*)alloc((size_t)NSEG*sizeof(int));
  float* invc = (float*)alloc((size_t)NSEG*sizeof(float));
  int*   offs = (int*)alloc((size_t)(NSEG+1)*sizeof(int));
  int*   cursor=(int*)alloc((size_t)NSEG*sizeof(int));
  int*   bsum = (int*)alloc((size_t)SC_NB*sizeof(int));
  int*   boff = (int*)alloc((size_t)SC_NB*sizeof(int));
  int*   esrc = (int*)alloc((size_t)NE*sizeof(int));
  float* W1eff= (float*)alloc((size_t)200*HD*sizeof(float));
  float* R1eff= (float*)alloc((size_t)50*HD*sizeof(float));
  unsigned short* B1t   = (unsigned short*)alloc((size_t)256*256*2);
  unsigned short* root2t= (unsigned short*)alloc((size_t)256*256*2);
  unsigned short* W2t   = (unsigned short*)alloc((size_t)256*1024*2);
  unsigned short* g1wt  = (unsigned short*)alloc((size_t)256*256*2);
  float* gate = (float*)alloc((size_t)NN*sizeof(float));
  float* expv = (float*)alloc((size_t)NN*sizeof(float));
  float* chan = (float*)alloc((size_t)2*HD*sizeof(float));
  float* bnp  = (float*)alloc((size_t)2*HD*sizeof(float));
  unsigned* gmaxk = (unsigned*)alloc((size_t)NBATCH*sizeof(unsigned));
  float* denom    = (float*)alloc((size_t)NBATCH*sizeof(float));
  float* pooled   = (float*)alloc((size_t)NBATCH*HD*sizeof(float));

  // ---- zero init ----
  hipMemsetAsync(hist, 0, (size_t)NSEG*50*sizeof(int), stream);
  hipMemsetAsync(cnt,  0, (size_t)NSEG*sizeof(int), stream);
  hipMemsetAsync(chan, 0, (size_t)2*HD*sizeof(float), stream);
  hipMemsetAsync(gmaxk,0, (size_t)NBATCH*sizeof(unsigned), stream);
  hipMemsetAsync(denom,0, (size_t)NBATCH*sizeof(float), stream);
  hipMemsetAsync(pooled,0,(size_t)NBATCH*HD*sizeof(float), stream);

  // ---- folded layer-1 weights (fp32), then bf16 transposed weight assembly ----
  k_weff<<<NR*50, HD, 0, stream>>>(emb0,emb1,emb2,emb3,emb4,emb5, W1, 384*HD, W1eff);
  k_weff<<<50,    HD, 0, stream>>>(emb0,emb1,emb2,emb3,emb4,emb5, root1, 0, R1eff);
  k_b1t<<<256, 256, 0, stream>>>(W1eff, R1eff, B1t);
  k_tconv<<<256, 256, 0, stream>>>(root2, root2t, 256, 256);
  k_tconv<<<1024, 256, 0, stream>>>(W2, W2t, 1024, 256);
  k_tconv<<<256, 256, 0, stream>>>(g1w, g1wt, 256, 256);

  // ---- histograms + counts + A1 ----
  k_hist<<<(NE+255)/256, 256, 0, stream>>>(ei, et, x, hist, cnt);
  k_invc<<<(NSEG+255)/256, 256, 0, stream>>>(cnt, invc);
  k_buildA<<<NN, 256, 0, stream>>>(x, hist, invc, A1);   // last read of hist

  // ---- layer 1 GEMM: h1 = sigmoid(A1 @ B1 + b1) ----
  dim3 gFull(2, (NN+127)/128);
  k_mfma<<<gFull, 256, 0, stream>>>(A1, B1t, b1, nullptr, h1, nullptr, NN, 256, 1);

  // ---- CSR build ----
  k_scan1<<<SC_NB, SC_T, 0, stream>>>(cnt, bsum);
  k_scan2<<<1, 256, 0, stream>>>(bsum, boff, offs);
  k_scan3<<<SC_NB, SC_T, 0, stream>>>(cnt, boff, offs, cursor);
  k_bin<<<(NE+255)/256, 256, 0, stream>>>(ei, et, cursor, esrc);

  // ---- layer 2: root GEMM, then chunked agg + K=1024 GEMM (in-place accum + sigmoid) ----
  k_mfma<<<gFull, 256, 0, stream>>>(h1, root2t, b2, nullptr, hRes, nullptr, NN, 256, 0);
  for (int c0 = 0; c0 < NN; c0 += CHUNK){
    int m = min(CHUNK, NN - c0);
    k_agg<<<(m*64+255)/256, 256, 0, stream>>>(offs, esrc, h1, agg, c0, m);
    dim3 gC(2, (m+127)/128);
    k_mfma<<<gC, 256, 0, stream>>>(agg, W2t, nullptr,
                                   hRes + (size_t)c0*HD, hRes + (size_t)c0*HD, nullptr,
                                   m, NR*HD, 1);
  }
  // hRes = h2 (bf16) now

  // ---- gate linear: g = h2 @ g1w + g1b (fp32 out), BN stats ----
  k_mfma<<<gFull, 256, 0, stream>>>(hRes, g1wt, g1b, nullptr, nullptr, g, NN, 256, 0);
  k_bnstats<<<(NN+127)/128, HD, 0, stream>>>(g, chan);
  k_bnfin<<<1, HD, 0, stream>>>(chan, bng, bnb, bnp);

  // ---- gate scalar + segment softmax + pooling ----
  k_gate<<<(NN+3)/4, 256, 0, stream>>>(g, bnp, g2w, g2b, batch, gate, gmaxk);
  k_exp<<<(NN+255)/256, 256, 0, stream>>>(gate, gmaxk, batch, expv, denom);
  k_pool<<<(NN+3)/4, 256, 0, stream>>>(hRes, expv, denom, batch, pooled);
  k_out<<<(NBATCH+3)/4, 256, 0, stream>>>(pooled, glw, glb, out);
}

// Round 8
// 911.587 us; speedup vs baseline: 3.6617x; 1.3244x over previous
//
#include <hip/hip_runtime.h>
#include <hip/hip_bf16.h>
#include <cstdint>

#define NN 50000      // nodes
#define NE 500000     // edges
#define NR 4          // relations
#define NBATCH 512    // graphs
#define HD 256        // hidden/out width
#define NSEG (NN*NR)  // 200000 (dst,rel) segments
#define CHUNK 10000   // nodes per agg/gemm chunk

__constant__ int c_off[6] = {0,33,38,41,45,47};   // cumulative CARD offsets (total 50)

__device__ __forceinline__ float sigf(float x){ return 1.0f/(1.0f+__expf(-x)); }
__device__ __forceinline__ float bf2f(unsigned short b){ return __uint_as_float((unsigned)b<<16); }
__device__ __forceinline__ unsigned short f2bf(float f){
  unsigned u = __float_as_uint(f);
  return (unsigned short)((u + 0x7fffu + ((u>>16)&1u)) >> 16);   // RNE
}

typedef short bf16raw8 __attribute__((ext_vector_type(8)));
typedef float f32x4v  __attribute__((ext_vector_type(4)));
union LD16 { uint4 u; bf16raw8 v; };

// ---------- folded weight precompute (fp32):  out[rc][h] = emb_j[cl] . W[r, j*64.. , h] ----------
__global__ void k_weff(const float* __restrict__ e0,const float* __restrict__ e1,
                       const float* __restrict__ e2,const float* __restrict__ e3,
                       const float* __restrict__ e4,const float* __restrict__ e5,
                       const float* __restrict__ W, int rstride,
                       float* __restrict__ out){
  int rc = blockIdx.x, h = threadIdx.x;
  int r = rc/50, cg = rc%50;
  int j, cl;
  if      (cg>=47){j=5;cl=cg-47;} else if (cg>=45){j=4;cl=cg-45;}
  else if (cg>=41){j=3;cl=cg-41;} else if (cg>=38){j=2;cl=cg-38;}
  else if (cg>=33){j=1;cl=cg-33;} else            {j=0;cl=cg;}
  const float* emb = j==0?e0:j==1?e1:j==2?e2:j==3?e3:j==4?e4:e5;
  const float* wb = W + (size_t)r*rstride + (size_t)(j*64)*HD + h;
  float acc = 0.f;
  #pragma unroll 8
  for (int k=0;k<64;k++) acc += emb[cl*64+k]*wb[(size_t)k*HD];
  out[(size_t)rc*HD+h] = acc;
}

// ---------- per-(dst,rel) histogram + segment counts ----------
__global__ void k_hist(const int* __restrict__ ei, const int* __restrict__ et,
                       const int* __restrict__ x, int* __restrict__ hist,
                       int* __restrict__ cnt){
  int e = blockIdx.x*256 + threadIdx.x;
  if (e >= NE) return;
  int s = ei[e], d = ei[NE+e], t = et[e];
  int seg = d*NR + t;
  atomicAdd(&cnt[seg], 1);
  int base = seg*50;
  #pragma unroll
  for (int j=0;j<6;j++){
    int c = x[s*6+j];
    atomicAdd(&hist[base + c_off[j] + c], 1);
  }
}

__global__ void k_invc(const int* __restrict__ cnt, float* __restrict__ invc){
  int i = blockIdx.x*256 + threadIdx.x;
  if (i >= NSEG) return;
  invc[i] = 1.0f / fmaxf((float)cnt[i], 1.0f);
}

// ---------- A1[n][256] bf16 = [200 hist-mean | 50 root one-hot | 6 zero] ----------
__global__ void k_buildA(const int* __restrict__ x, const int* __restrict__ hist,
                         const float* __restrict__ invc, unsigned short* __restrict__ A1){
  int n = blockIdx.x, tid = threadIdx.x;
  float v = 0.f;
  if (tid < 200){
    v = (float)hist[(size_t)n*200 + tid] * invc[n*4 + (tid/50)];
  } else if (tid < 250){
    int cg = tid - 200;
    #pragma unroll
    for (int j=0;j<6;j++) if (cg == c_off[j] + x[n*6+j]) v = 1.f;
  }
  A1[(size_t)n*256 + tid] = f2bf(v);
}

// ---------- B1t[o][k] bf16 from W1eff(200 rows)+R1eff(50 rows), zero-padded to 256 ----------
__global__ void k_b1t(const float* __restrict__ W1eff, const float* __restrict__ R1eff,
                      unsigned short* __restrict__ B1t){
  int id = blockIdx.x*256 + threadIdx.x;      // 256*256 total
  int k = id & 255, o = id >> 8;
  float v = 0.f;
  if (k < 200) v = W1eff[(size_t)k*HD + o];
  else if (k < 250) v = R1eff[(size_t)(k-200)*HD + o];
  B1t[(size_t)o*256 + k] = f2bf(v);
}

// ---------- transpose+convert fp32 W[K][O] -> bf16 Wt[O][K] ----------
__global__ void k_tconv(const float* __restrict__ W, unsigned short* __restrict__ Wt,
                        int K, int O){
  int id = blockIdx.x*256 + threadIdx.x;
  if (id >= K*O) return;
  int k = id % K, o = id / K;
  Wt[(size_t)o*K + k] = f2bf(W[(size_t)k*O + o]);
}

// ---------- 3-kernel exclusive prefix scan over cnt[NSEG] ----------
#define SC_T 256
#define SC_NB ((NSEG/4 + SC_T - 1)/SC_T)   // 196 blocks

__global__ void k_scan1(const int* __restrict__ cnt, int* __restrict__ bsum){
  __shared__ int sh[SC_T];
  int b = blockIdx.x, t = threadIdx.x;
  int i4 = b*SC_T + t;
  int s = 0;
  if (i4 < NSEG/4){ int4 v = ((const int4*)cnt)[i4]; s = v.x+v.y+v.z+v.w; }
  sh[t] = s; __syncthreads();
  for (int o=128;o>0;o>>=1){ if (t<o) sh[t]+=sh[t+o]; __syncthreads(); }
  if (t==0) bsum[b] = sh[0];
}

__global__ void k_scan2(const int* __restrict__ bsum, int* __restrict__ boff,
                        int* __restrict__ offs){
  __shared__ int sh[256];
  int t = threadIdx.x;
  int v = (t < SC_NB) ? bsum[t] : 0;
  sh[t] = v; __syncthreads();
  for (int o=1;o<256;o<<=1){
    int add = (t>=o) ? sh[t-o] : 0; __syncthreads();
    sh[t] += add; __syncthreads();
  }
  if (t < SC_NB) boff[t] = sh[t] - v;
  if (t == 255) offs[NSEG] = sh[255];
}

__global__ void k_scan3(const int* __restrict__ cnt, const int* __restrict__ boff,
                        int* __restrict__ offs, int* __restrict__ cursor){
  __shared__ int sh[SC_T];
  int b = blockIdx.x, t = threadIdx.x;
  int i4 = b*SC_T + t;
  int4 v = {0,0,0,0};
  if (i4 < NSEG/4) v = ((const int4*)cnt)[i4];
  int s = v.x+v.y+v.z+v.w;
  sh[t] = s; __syncthreads();
  for (int o=1;o<256;o<<=1){
    int add = (t>=o) ? sh[t-o] : 0; __syncthreads();
    sh[t] += add; __syncthreads();
  }
  if (i4 < NSEG/4){
    int excl = sh[t] - s + boff[b];
    int4 ov; ov.x = excl; ov.y = ov.x+v.x; ov.z = ov.y+v.y; ov.w = ov.z+v.z;
    ((int4*)offs)[i4] = ov; ((int4*)cursor)[i4] = ov;
  }
}

// ---------- bin edges into CSR slots by (dst,rel) ----------
__global__ void k_bin(const int* __restrict__ ei, const int* __restrict__ et,
                      int* __restrict__ cursor, int* __restrict__ esrc){
  int e = blockIdx.x*256 + threadIdx.x;
  if (e >= NE) return;
  int s = ei[e], d = ei[NE+e], t = et[e];
  int slot = atomicAdd(&cursor[d*NR + t], 1);
  esrc[slot] = s;
}

// ---------- gather-aggregate (bf16 in/out, fp32 accum) ----------
__global__ void k_agg(const int* __restrict__ offs, const int* __restrict__ esrc,
                      const unsigned short* __restrict__ h1, unsigned short* __restrict__ agg,
                      int base, int m){
  int gid = blockIdx.x*256 + threadIdx.x;
  int n = gid >> 6;          // one wave per node
  if (n >= m) return;
  int lane = gid & 63;
  int gn = base + n;
  #pragma unroll
  for (int r=0;r<NR;r++){
    int a = offs[gn*NR+r], b = offs[gn*NR+r+1];
    float a0=0.f,a1=0.f,a2=0.f,a3=0.f;
    for (int e=a;e<b;e++){
      int s = esrc[e];
      ushort4 v = *(const ushort4*)(h1 + (size_t)s*HD + lane*4);
      a0+=bf2f(v.x); a1+=bf2f(v.y); a2+=bf2f(v.z); a3+=bf2f(v.w);
    }
    float iv = 1.0f / (float)max(b-a, 1);
    ushort4 o;
    o.x=f2bf(a0*iv); o.y=f2bf(a1*iv); o.z=f2bf(a2*iv); o.w=f2bf(a3*iv);
    *(ushort4*)(agg + (size_t)n*(NR*HD) + r*HD + lane*4) = o;
  }
}

// ---------- bf16 MFMA GEMM, no LDS: C[M,256] = A[M,K] @ Bt[256,K]^T (+bias)(+Cin)(+sigmoid) ----------
__global__ __launch_bounds__(256) void k_mfma(
    const unsigned short* __restrict__ A,    // [M][K] bf16
    const unsigned short* __restrict__ Bt,   // [256][K] bf16 (pre-transposed)
    const float* __restrict__ bias,          // [256] or null
    const unsigned short* __restrict__ Cin,  // [M][256] bf16 or null (added)
    unsigned short* __restrict__ outB,       // [M][256] bf16 or null
    float* __restrict__ outF,                // [M][256] f32 or null
    int M, int K, int actsig){
  int tid = threadIdx.x;
  int wave = tid >> 6, lane = tid & 63;
  int wm = (wave >> 1) * 64, wn = (wave & 1) * 64;
  int bm = blockIdx.y * 128, bn = blockIdx.x * 128;
  int lrow = lane & 15, lk8 = (lane >> 4) * 8;

  f32x4v acc[4][4] = {};
  for (int k0 = 0; k0 < K; k0 += 32){
    bf16raw8 aF[4], bF[4];
    #pragma unroll
    for (int mi = 0; mi < 4; mi++){
      int row = bm + wm + mi*16 + lrow; if (row > M-1) row = M-1;
      LD16 t; t.u = *(const uint4*)(A + (size_t)row*K + k0 + lk8); aF[mi] = t.v;
    }
    #pragma unroll
    for (int nj = 0; nj < 4; nj++){
      int col = bn + wn + nj*16 + lrow;   // always < 256
      LD16 t; t.u = *(const uint4*)(Bt + (size_t)col*K + k0 + lk8); bF[nj] = t.v;
    }
    #pragma unroll
    for (int mi = 0; mi < 4; mi++)
      #pragma unroll
      for (int nj = 0; nj < 4; nj++)
        acc[mi][nj] = __builtin_amdgcn_mfma_f32_16x16x32_bf16(aF[mi], bF[nj], acc[mi][nj], 0, 0, 0);
  }
  int r0 = (lane >> 4) * 4;
  #pragma unroll
  for (int mi = 0; mi < 4; mi++){
    #pragma unroll
    for (int i = 0; i < 4; i++){
      int row = bm + wm + mi*16 + r0 + i;
      if (row >= M) continue;
      #pragma unroll
      for (int nj = 0; nj < 4; nj++){
        int col = bn + wn + nj*16 + lrow;
        float v = acc[mi][nj][i];
        if (bias) v += bias[col];
        if (Cin)  v += bf2f(Cin[(size_t)row*HD + col]);
        if (actsig) v = sigf(v);
        if (outB) outB[(size_t)row*HD + col] = f2bf(v);
        if (outF) outF[(size_t)row*HD + col] = v;
      }
    }
  }
}

// ---------- BN stats (training-mode, biased var) ----------
__global__ void k_bnstats(const float* __restrict__ g, float* __restrict__ chan){
  int c = threadIdx.x;
  int r0 = blockIdx.x*128;
  int rend = min(r0+128, NN);
  float s=0.f, q=0.f;
  for (int row=r0; row<rend; row++){
    float v = g[(size_t)row*HD + c];
    s += v; q += v*v;
  }
  atomicAdd(&chan[c], s); atomicAdd(&chan[HD+c], q);
}

__global__ void k_bnfin(const float* __restrict__ chan, const float* __restrict__ bng,
                        const float* __restrict__ bnb, float* __restrict__ bnp){
  int c = threadIdx.x;
  float mu = chan[c]/(float)NN;
  float var = chan[HD+c]/(float)NN - mu*mu;
  float scale = bng[c]*rsqrtf(var + 1e-5f);
  bnp[c] = bnb[c] - mu*scale;     // shift
  bnp[HD+c] = scale;              // scale
}

// ---------- gate[n] = relu(BN(g[n])) . g2_w + g2_b (no atomics) ----------
__global__ void k_gate(const float* __restrict__ g, const float* __restrict__ bnp,
                       const float* __restrict__ g2w, const float* __restrict__ g2b,
                       float* __restrict__ gate){
  int lane = threadIdx.x & 63;
  int n = blockIdx.x*4 + (threadIdx.x>>6);
  if (n >= NN) return;
  float s = 0.f;
  #pragma unroll
  for (int k=0;k<4;k++){
    int c = lane + k*64;
    float v = g[(size_t)n*HD + c]*bnp[HD+c] + bnp[c];
    v = fmaxf(v, 0.f);
    s += v * g2w[c];
  }
  #pragma unroll
  for (int o=32;o>0;o>>=1) s += __shfl_down(s, o);
  if (lane==0) gate[n] = s + g2b[0];
}

// ---------- per-graph offsets from SORTED batch ----------
__global__ void k_goffs(const int* __restrict__ batch, int* __restrict__ goffs){
  int n = blockIdx.x*256 + threadIdx.x;
  if (n >= NN) return;
  int b = batch[n];
  int prev = (n == 0) ? -1 : batch[n-1];
  for (int gg = prev+1; gg <= b; gg++) goffs[gg] = n;
  if (n == NN-1){ for (int gg = b+1; gg <= NBATCH; gg++) goffs[gg] = NN; }
}

// ---------- fused per-graph: softmax(gate) -> weighted pool of h2 -> out = sigmoid(.glw+glb) ----------
__global__ __launch_bounds__(256) void k_poolg(
    const unsigned short* __restrict__ h2, const float* __restrict__ gate,
    const int* __restrict__ goffs, const float* __restrict__ glw,
    const float* __restrict__ glb, float* __restrict__ out){
  __shared__ float red[256];
  int b = blockIdx.x, tid = threadIdx.x;
  int a = goffs[b], e = goffs[b+1];

  // phase 1: max over gate[a:e]
  float m = -3.4e38f;
  for (int n = a + tid; n < e; n += 256) m = fmaxf(m, gate[n]);
  red[tid] = m; __syncthreads();
  for (int o = 128; o > 0; o >>= 1){ if (tid < o) red[tid] = fmaxf(red[tid], red[tid+o]); __syncthreads(); }
  m = red[0]; __syncthreads();

  // phase 2: sum of exp
  float s = 0.f;
  for (int n = a + tid; n < e; n += 256) s += __expf(gate[n] - m);
  red[tid] = s; __syncthreads();
  for (int o = 128; o > 0; o >>= 1){ if (tid < o) red[tid] += red[tid+o]; __syncthreads(); }
  float denom = red[0] + 1e-16f; __syncthreads();

  // phase 3: per-channel weighted accumulate (tid = channel)
  float acc = 0.f;
  #pragma unroll 4
  for (int n = a; n < e; n++){
    float ev = __expf(gate[n] - m);
    acc += ev * bf2f(h2[(size_t)n*HD + tid]);
  }
  acc /= denom;

  // phase 4: dot with glw -> out
  red[tid] = acc * glw[tid]; __syncthreads();
  for (int o = 128; o > 0; o >>= 1){ if (tid < o) red[tid] += red[tid+o]; __syncthreads(); }
  if (tid == 0) out[b] = sigf(red[0] + glb[0]);
}

extern "C" void kernel_launch(void* const* d_in, const int* in_sizes, int n_in,
                              void* d_out, int out_size, void* d_ws, size_t ws_size,
                              hipStream_t stream) {
  const int* x     = (const int*)d_in[0];
  const int* ei    = (const int*)d_in[1];
  const int* et    = (const int*)d_in[2];
  const int* batch = (const int*)d_in[3];
  const float* emb0 = (const float*)d_in[4];
  const float* emb1 = (const float*)d_in[5];
  const float* emb2 = (const float*)d_in[6];
  const float* emb3 = (const float*)d_in[7];
  const float* emb4 = (const float*)d_in[8];
  const float* emb5 = (const float*)d_in[9];
  const float* W1    = (const float*)d_in[10];
  const float* root1 = (const float*)d_in[11];
  const float* b1    = (const float*)d_in[12];
  const float* W2    = (const float*)d_in[13];  // [R,H,O] flat == [1024,256]
  const float* root2 = (const float*)d_in[14];
  const float* b2    = (const float*)d_in[15];
  const float* g1w   = (const float*)d_in[16];
  const float* g1b   = (const float*)d_in[17];
  const float* bng   = (const float*)d_in[18];
  const float* bnb   = (const float*)d_in[19];
  const float* g2w   = (const float*)d_in[20];
  const float* g2b   = (const float*)d_in[21];
  const float* glw   = (const float*)d_in[22];
  const float* glb   = (const float*)d_in[23];
  float* out = (float*)d_out;

  // ---- workspace carve-up (256B aligned), total ≈ 150 MB ----
  char* w = (char*)d_ws;
  auto alloc = [&](size_t bytes)->char* {
    char* p = w; w += (bytes + 255) & ~(size_t)255; return p;
  };
  char* histReg = alloc((size_t)NSEG*50*sizeof(int));   // hist, later agg
  int*  hist = (int*)histReg;
  unsigned short* agg = (unsigned short*)histReg;
  char* gReg = alloc((size_t)NN*HD*sizeof(float));      // A1 (bf16), later g (f32)
  unsigned short* A1 = (unsigned short*)gReg;
  float* g = (float*)gReg;
  unsigned short* h1   = (unsigned short*)alloc((size_t)NN*HD*2);
  unsigned short* hRes = (unsigned short*)alloc((size_t)NN*HD*2);
  int*   cnt  = (int*)alloc((size_t)NSEG*sizeof(int));
  float* invc = (float*)alloc((size_t)NSEG*sizeof(float));
  int*   offs = (int*)alloc((size_t)(NSEG+1)*sizeof(int));
  int*   cursor=(int*)alloc((size_t)NSEG*sizeof(int));
  int*   bsum = (int*)alloc((size_t)SC_NB*sizeof(int));
  int*   boff = (int*)alloc((size_t)SC_NB*sizeof(int));
  int*   esrc = (int*)alloc((size_t)NE*sizeof(int));
  float* W1eff= (float*)alloc((size_t)200*HD*sizeof(float));
  float* R1eff= (float*)alloc((size_t)50*HD*sizeof(float));
  unsigned short* B1t   = (unsigned short*)alloc((size_t)256*256*2);
  unsigned short* root2t= (unsigned short*)alloc((size_t)256*256*2);
  unsigned short* W2t   = (unsigned short*)alloc((size_t)256*1024*2);
  unsigned short* g1wt  = (unsigned short*)alloc((size_t)256*256*2);
  float* gate = (float*)alloc((size_t)NN*sizeof(float));
  int*   goffs= (int*)alloc((size_t)(NBATCH+1)*sizeof(int));
  float* chan = (float*)alloc((size_t)2*HD*sizeof(float));
  float* bnp  = (float*)alloc((size_t)2*HD*sizeof(float));

  // ---- zero init ----
  hipMemsetAsync(hist, 0, (size_t)NSEG*50*sizeof(int), stream);
  hipMemsetAsync(cnt,  0, (size_t)NSEG*sizeof(int), stream);
  hipMemsetAsync(chan, 0, (size_t)2*HD*sizeof(float), stream);

  // ---- folded layer-1 weights (fp32), then bf16 transposed weight assembly ----
  k_weff<<<NR*50, HD, 0, stream>>>(emb0,emb1,emb2,emb3,emb4,emb5, W1, 384*HD, W1eff);
  k_weff<<<50,    HD, 0, stream>>>(emb0,emb1,emb2,emb3,emb4,emb5, root1, 0, R1eff);
  k_b1t<<<256, 256, 0, stream>>>(W1eff, R1eff, B1t);
  k_tconv<<<256, 256, 0, stream>>>(root2, root2t, 256, 256);
  k_tconv<<<1024, 256, 0, stream>>>(W2, W2t, 1024, 256);
  k_tconv<<<256, 256, 0, stream>>>(g1w, g1wt, 256, 256);

  // ---- histograms + counts + A1 ----
  k_hist<<<(NE+255)/256, 256, 0, stream>>>(ei, et, x, hist, cnt);
  k_invc<<<(NSEG+255)/256, 256, 0, stream>>>(cnt, invc);
  k_buildA<<<NN, 256, 0, stream>>>(x, hist, invc, A1);   // last read of hist

  // ---- layer 1 GEMM: h1 = sigmoid(A1 @ B1 + b1) ----
  dim3 gFull(2, (NN+127)/128);
  k_mfma<<<gFull, 256, 0, stream>>>(A1, B1t, b1, nullptr, h1, nullptr, NN, 256, 1);

  // ---- CSR build ----
  k_scan1<<<SC_NB, SC_T, 0, stream>>>(cnt, bsum);
  k_scan2<<<1, 256, 0, stream>>>(bsum, boff, offs);
  k_scan3<<<SC_NB, SC_T, 0, stream>>>(cnt, boff, offs, cursor);
  k_bin<<<(NE+255)/256, 256, 0, stream>>>(ei, et, cursor, esrc);

  // ---- per-graph offsets ----
  k_goffs<<<(NN+255)/256, 256, 0, stream>>>(batch, goffs);

  // ---- layer 2: root GEMM, then chunked agg + K=1024 GEMM (in-place accum + sigmoid) ----
  k_mfma<<<gFull, 256, 0, stream>>>(h1, root2t, b2, nullptr, hRes, nullptr, NN, 256, 0);
  for (int c0 = 0; c0 < NN; c0 += CHUNK){
    int m = min(CHUNK, NN - c0);
    k_agg<<<(m*64+255)/256, 256, 0, stream>>>(offs, esrc, h1, agg, c0, m);
    dim3 gC(2, (m+127)/128);
    k_mfma<<<gC, 256, 0, stream>>>(agg, W2t, nullptr,
                                   hRes + (size_t)c0*HD, hRes + (size_t)c0*HD, nullptr,
                                   m, NR*HD, 1);
  }
  // hRes = h2 (bf16)

  // ---- gate linear: g = h2 @ g1w + g1b (fp32 out), BN stats ----
  k_mfma<<<gFull, 256, 0, stream>>>(hRes, g1wt, g1b, nullptr, nullptr, g, NN, 256, 0);
  k_bnstats<<<(NN+127)/128, HD, 0, stream>>>(g, chan);
  k_bnfin<<<1, HD, 0, stream>>>(chan, bng, bnb, bnp);

  // ---- gate scalar (no atomics) + fused per-graph softmax/pool/output ----
  k_gate<<<(NN+3)/4, 256, 0, stream>>>(g, bnp, g2w, g2b, gate);
  k_poolg<<<NBATCH, 256, 0, stream>>>(hRes, gate, goffs, glw, glb, out);
}

// Round 9
// 768.258 us; speedup vs baseline: 4.3448x; 1.1866x over previous
//
#include <hip/hip_runtime.h>
#include <hip/hip_bf16.h>
#include <cstdint>

#define NN 50000      // nodes
#define NE 500000     // edges
#define NR 4          // relations
#define NBATCH 512    // graphs
#define HD 256        // hidden/out width
#define NSEG (NN*NR)  // 200000 (dst,rel) segments
#define CHUNK 10000   // nodes per agg/gemm chunk

__constant__ int c_off[6] = {0,33,38,41,45,47};   // cumulative CARD offsets (total 50)

__device__ __forceinline__ float sigf(float x){ return 1.0f/(1.0f+__expf(-x)); }
__device__ __forceinline__ float bf2f(unsigned short b){ return __uint_as_float((unsigned)b<<16); }
__device__ __forceinline__ unsigned short f2bf(float f){
  unsigned u = __float_as_uint(f);
  return (unsigned short)((u + 0x7fffu + ((u>>16)&1u)) >> 16);   // RNE
}

typedef short bf16raw8 __attribute__((ext_vector_type(8)));
typedef float f32x4v  __attribute__((ext_vector_type(4)));
union LD16 { uint4 u; bf16raw8 v; };

// ---------- folded weight precompute (fp32):  out[rc][h] = emb_j[cl] . W[r, j*64.. , h] ----------
__global__ void k_weff(const float* __restrict__ e0,const float* __restrict__ e1,
                       const float* __restrict__ e2,const float* __restrict__ e3,
                       const float* __restrict__ e4,const float* __restrict__ e5,
                       const float* __restrict__ W, int rstride,
                       float* __restrict__ out){
  int rc = blockIdx.x, h = threadIdx.x;
  int r = rc/50, cg = rc%50;
  int j, cl;
  if      (cg>=47){j=5;cl=cg-47;} else if (cg>=45){j=4;cl=cg-45;}
  else if (cg>=41){j=3;cl=cg-41;} else if (cg>=38){j=2;cl=cg-38;}
  else if (cg>=33){j=1;cl=cg-33;} else            {j=0;cl=cg;}
  const float* emb = j==0?e0:j==1?e1:j==2?e2:j==3?e3:j==4?e4:e5;
  const float* wb = W + (size_t)r*rstride + (size_t)(j*64)*HD + h;
  float acc = 0.f;
  #pragma unroll 8
  for (int k=0;k<64;k++) acc += emb[cl*64+k]*wb[(size_t)k*HD];
  out[(size_t)rc*HD+h] = acc;
}

// ---------- segment counts only (cnt is 800KB, L2-resident) ----------
__global__ void k_cnt(const int* __restrict__ ei, const int* __restrict__ et,
                      int* __restrict__ cnt){
  int e = blockIdx.x*256 + threadIdx.x;
  if (e >= NE) return;
  atomicAdd(&cnt[ei[NE+e]*NR + et[e]], 1);
}

// ---------- B1t[o][k] bf16 from W1eff(200 rows)+R1eff(50 rows), zero-padded to 256 ----------
__global__ void k_b1t(const float* __restrict__ W1eff, const float* __restrict__ R1eff,
                      unsigned short* __restrict__ B1t){
  int id = blockIdx.x*256 + threadIdx.x;      // 256*256 total
  int k = id & 255, o = id >> 8;
  float v = 0.f;
  if (k < 200) v = W1eff[(size_t)k*HD + o];
  else if (k < 250) v = R1eff[(size_t)(k-200)*HD + o];
  B1t[(size_t)o*256 + k] = f2bf(v);
}

// ---------- transpose+convert fp32 W[K][O] -> bf16 Wt[o][dstOff+k] (row stride dstStride) ----------
__global__ void k_tconv(const float* __restrict__ W, unsigned short* __restrict__ Wt,
                        int K, int O, int dstStride, int dstOff){
  int id = blockIdx.x*256 + threadIdx.x;
  if (id >= K*O) return;
  int k = id % K, o = id / K;
  Wt[(size_t)o*dstStride + dstOff + k] = f2bf(W[(size_t)k*O + o]);
}

// ---------- 3-kernel exclusive prefix scan over cnt[NSEG] ----------
#define SC_T 256
#define SC_NB ((NSEG/4 + SC_T - 1)/SC_T)   // 196 blocks

__global__ void k_scan1(const int* __restrict__ cnt, int* __restrict__ bsum){
  __shared__ int sh[SC_T];
  int b = blockIdx.x, t = threadIdx.x;
  int i4 = b*SC_T + t;
  int s = 0;
  if (i4 < NSEG/4){ int4 v = ((const int4*)cnt)[i4]; s = v.x+v.y+v.z+v.w; }
  sh[t] = s; __syncthreads();
  for (int o=128;o>0;o>>=1){ if (t<o) sh[t]+=sh[t+o]; __syncthreads(); }
  if (t==0) bsum[b] = sh[0];
}

__global__ void k_scan2(const int* __restrict__ bsum, int* __restrict__ boff,
                        int* __restrict__ offs){
  __shared__ int sh[256];
  int t = threadIdx.x;
  int v = (t < SC_NB) ? bsum[t] : 0;
  sh[t] = v; __syncthreads();
  for (int o=1;o<256;o<<=1){
    int add = (t>=o) ? sh[t-o] : 0; __syncthreads();
    sh[t] += add; __syncthreads();
  }
  if (t < SC_NB) boff[t] = sh[t] - v;
  if (t == 255) offs[NSEG] = sh[255];
}

__global__ void k_scan3(const int* __restrict__ cnt, const int* __restrict__ boff,
                        int* __restrict__ offs, int* __restrict__ cursor){
  __shared__ int sh[SC_T];
  int b = blockIdx.x, t = threadIdx.x;
  int i4 = b*SC_T + t;
  int4 v = {0,0,0,0};
  if (i4 < NSEG/4) v = ((const int4*)cnt)[i4];
  int s = v.x+v.y+v.z+v.w;
  sh[t] = s; __syncthreads();
  for (int o=1;o<256;o<<=1){
    int add = (t>=o) ? sh[t-o] : 0; __syncthreads();
    sh[t] += add; __syncthreads();
  }
  if (i4 < NSEG/4){
    int excl = sh[t] - s + boff[b];
    int4 ov; ov.x = excl; ov.y = ov.x+v.x; ov.z = ov.y+v.y; ov.w = ov.z+v.z;
    ((int4*)offs)[i4] = ov; ((int4*)cursor)[i4] = ov;
  }
}

// ---------- bin edges into CSR slots by (dst,rel) ----------
__global__ void k_bin(const int* __restrict__ ei, const int* __restrict__ et,
                      int* __restrict__ cursor, int* __restrict__ esrc){
  int e = blockIdx.x*256 + threadIdx.x;
  if (e >= NE) return;
  int s = ei[e], d = ei[NE+e], t = et[e];
  int slot = atomicAdd(&cursor[d*NR + t], 1);
  esrc[slot] = s;
}

// ---------- A1[n][256] from CSR gather (replaces scatter histogram):
//            t<200: (r,bin) count/cnt ; t in [200,250): root one-hot ; else 0 ----------
__global__ void k_buildseg(const int* __restrict__ x, const int* __restrict__ offs,
                           const int* __restrict__ esrc, unsigned short* __restrict__ A1){
  int n = blockIdx.x, t = threadIdx.x;
  float v = 0.f;
  if (t < 200){
    int r = t/50, bin = t%50;
    int j, cl;
    if      (bin>=47){j=5;cl=bin-47;} else if (bin>=45){j=4;cl=bin-45;}
    else if (bin>=41){j=3;cl=bin-41;} else if (bin>=38){j=2;cl=bin-38;}
    else if (bin>=33){j=1;cl=bin-33;} else            {j=0;cl=bin;}
    int a = offs[n*NR+r], e2 = offs[n*NR+r+1];
    int c = 0;
    for (int e=a;e<e2;e++){
      int s = esrc[e];
      c += (x[s*6+j] == cl) ? 1 : 0;
    }
    v = (float)c / (float)max(e2-a, 1);
  } else if (t < 250){
    int cg = t - 200;
    #pragma unroll
    for (int j=0;j<6;j++) if (cg == c_off[j] + x[n*6+j]) v = 1.f;
  }
  A1[(size_t)n*256 + t] = f2bf(v);
}

// ---------- gather-aggregate (bf16 in/out, fp32 accum) ----------
__global__ void k_agg(const int* __restrict__ offs, const int* __restrict__ esrc,
                      const unsigned short* __restrict__ h1, unsigned short* __restrict__ agg,
                      int base, int m){
  int gid = blockIdx.x*256 + threadIdx.x;
  int n = gid >> 6;          // one wave per node
  if (n >= m) return;
  int lane = gid & 63;
  int gn = base + n;
  #pragma unroll
  for (int r=0;r<NR;r++){
    int a = offs[gn*NR+r], b = offs[gn*NR+r+1];
    float a0=0.f,a1=0.f,a2=0.f,a3=0.f;
    for (int e=a;e<b;e++){
      int s = esrc[e];
      ushort4 v = *(const ushort4*)(h1 + (size_t)s*HD + lane*4);
      a0+=bf2f(v.x); a1+=bf2f(v.y); a2+=bf2f(v.z); a3+=bf2f(v.w);
    }
    float iv = 1.0f / (float)max(b-a, 1);
    ushort4 o;
    o.x=f2bf(a0*iv); o.y=f2bf(a1*iv); o.z=f2bf(a2*iv); o.w=f2bf(a3*iv);
    *(ushort4*)(agg + (size_t)n*(NR*HD) + r*HD + lane*4) = o;
  }
}

// ---------- bf16 MFMA GEMM, no LDS, dual-A: C[M,256] = [A|A2] @ Bt^T (+bias)(+sigmoid) ----------
// A covers k in [0,K1) with row stride lda; A2 covers [K1,K) with row stride lda2.
__global__ __launch_bounds__(256) void k_mfma(
    const unsigned short* __restrict__ A,    // [M][lda] bf16
    int lda, int K1,
    const unsigned short* __restrict__ A2,   // [M][lda2] bf16 or null
    int lda2,
    const unsigned short* __restrict__ Bt,   // [256][K] bf16 (pre-transposed, row stride K)
    const float* __restrict__ bias,          // [256] or null
    unsigned short* __restrict__ outB,       // [M][256] bf16 or null
    float* __restrict__ outF,                // [M][256] f32 or null
    int M, int K, int actsig){
  int tid = threadIdx.x;
  int wave = tid >> 6, lane = tid & 63;
  int wm = (wave >> 1) * 64, wn = (wave & 1) * 64;
  int bm = blockIdx.y * 128, bn = blockIdx.x * 128;
  int lrow = lane & 15, lk8 = (lane >> 4) * 8;

  f32x4v acc[4][4] = {};
  for (int k0 = 0; k0 < K; k0 += 32){
    bf16raw8 aF[4], bF[4];
    const unsigned short* Ap = (k0 < K1) ? A : A2;
    int stride = (k0 < K1) ? lda : lda2;
    int kk0 = (k0 < K1) ? k0 : (k0 - K1);
    #pragma unroll
    for (int mi = 0; mi < 4; mi++){
      int row = bm + wm + mi*16 + lrow; if (row > M-1) row = M-1;
      LD16 t; t.u = *(const uint4*)(Ap + (size_t)row*stride + kk0 + lk8); aF[mi] = t.v;
    }
    #pragma unroll
    for (int nj = 0; nj < 4; nj++){
      int col = bn + wn + nj*16 + lrow;   // always < 256
      LD16 t; t.u = *(const uint4*)(Bt + (size_t)col*K + k0 + lk8); bF[nj] = t.v;
    }
    #pragma unroll
    for (int mi = 0; mi < 4; mi++)
      #pragma unroll
      for (int nj = 0; nj < 4; nj++)
        acc[mi][nj] = __builtin_amdgcn_mfma_f32_16x16x32_bf16(aF[mi], bF[nj], acc[mi][nj], 0, 0, 0);
  }
  int r0 = (lane >> 4) * 4;
  #pragma unroll
  for (int mi = 0; mi < 4; mi++){
    #pragma unroll
    for (int i = 0; i < 4; i++){
      int row = bm + wm + mi*16 + r0 + i;
      if (row >= M) continue;
      #pragma unroll
      for (int nj = 0; nj < 4; nj++){
        int col = bn + wn + nj*16 + lrow;
        float v = acc[mi][nj][i];
        if (bias) v += bias[col];
        if (actsig) v = sigf(v);
        if (outB) outB[(size_t)row*HD + col] = f2bf(v);
        if (outF) outF[(size_t)row*HD + col] = v;
      }
    }
  }
}

// ---------- BN stats (training-mode, biased var) ----------
__global__ void k_bnstats(const float* __restrict__ g, float* __restrict__ chan){
  int c = threadIdx.x;
  int r0 = blockIdx.x*128;
  int rend = min(r0+128, NN);
  float s=0.f, q=0.f;
  for (int row=r0; row<rend; row++){
    float v = g[(size_t)row*HD + c];
    s += v; q += v*v;
  }
  atomicAdd(&chan[c], s); atomicAdd(&chan[HD+c], q);
}

__global__ void k_bnfin(const float* __restrict__ chan, const float* __restrict__ bng,
                        const float* __restrict__ bnb, float* __restrict__ bnp){
  int c = threadIdx.x;
  float mu = chan[c]/(float)NN;
  float var = chan[HD+c]/(float)NN - mu*mu;
  float scale = bng[c]*rsqrtf(var + 1e-5f);
  bnp[c] = bnb[c] - mu*scale;     // shift
  bnp[HD+c] = scale;              // scale
}

// ---------- gate[n] = relu(BN(g[n])) . g2_w + g2_b (no atomics) ----------
__global__ void k_gate(const float* __restrict__ g, const float* __restrict__ bnp,
                       const float* __restrict__ g2w, const float* __restrict__ g2b,
                       float* __restrict__ gate){
  int lane = threadIdx.x & 63;
  int n = blockIdx.x*4 + (threadIdx.x>>6);
  if (n >= NN) return;
  float s = 0.f;
  #pragma unroll
  for (int k=0;k<4;k++){
    int c = lane + k*64;
    float v = g[(size_t)n*HD + c]*bnp[HD+c] + bnp[c];
    v = fmaxf(v, 0.f);
    s += v * g2w[c];
  }
  #pragma unroll
  for (int o=32;o>0;o>>=1) s += __shfl_down(s, o);
  if (lane==0) gate[n] = s + g2b[0];
}

// ---------- per-graph offsets from SORTED batch ----------
__global__ void k_goffs(const int* __restrict__ batch, int* __restrict__ goffs){
  int n = blockIdx.x*256 + threadIdx.x;
  if (n >= NN) return;
  int b = batch[n];
  int prev = (n == 0) ? -1 : batch[n-1];
  for (int gg = prev+1; gg <= b; gg++) goffs[gg] = n;
  if (n == NN-1){ for (int gg = b+1; gg <= NBATCH; gg++) goffs[gg] = NN; }
}

// ---------- fused per-graph: softmax(gate) -> weighted pool of h2 -> out = sigmoid(.glw+glb) ----------
__global__ __launch_bounds__(256) void k_poolg(
    const unsigned short* __restrict__ h2, const float* __restrict__ gate,
    const int* __restrict__ goffs, const float* __restrict__ glw,
    const float* __restrict__ glb, float* __restrict__ out){
  __shared__ float red[256];
  int b = blockIdx.x, tid = threadIdx.x;
  int a = goffs[b], e = goffs[b+1];

  // phase 1: max over gate[a:e]
  float m = -3.4e38f;
  for (int n = a + tid; n < e; n += 256) m = fmaxf(m, gate[n]);
  red[tid] = m; __syncthreads();
  for (int o = 128; o > 0; o >>= 1){ if (tid < o) red[tid] = fmaxf(red[tid], red[tid+o]); __syncthreads(); }
  m = red[0]; __syncthreads();

  // phase 2: sum of exp
  float s = 0.f;
  for (int n = a + tid; n < e; n += 256) s += __expf(gate[n] - m);
  red[tid] = s; __syncthreads();
  for (int o = 128; o > 0; o >>= 1){ if (tid < o) red[tid] += red[tid+o]; __syncthreads(); }
  float denom = red[0] + 1e-16f; __syncthreads();

  // phase 3: per-channel weighted accumulate (tid = channel)
  float acc = 0.f;
  #pragma unroll 4
  for (int n = a; n < e; n++){
    float ev = __expf(gate[n] - m);
    acc += ev * bf2f(h2[(size_t)n*HD + tid]);
  }
  acc /= denom;

  // phase 4: dot with glw -> out
  red[tid] = acc * glw[tid]; __syncthreads();
  for (int o = 128; o > 0; o >>= 1){ if (tid < o) red[tid] += red[tid+o]; __syncthreads(); }
  if (tid == 0) out[b] = sigf(red[0] + glb[0]);
}

extern "C" void kernel_launch(void* const* d_in, const int* in_sizes, int n_in,
                              void* d_out, int out_size, void* d_ws, size_t ws_size,
                              hipStream_t stream) {
  const int* x     = (const int*)d_in[0];
  const int* ei    = (const int*)d_in[1];
  const int* et    = (const int*)d_in[2];
  const int* batch = (const int*)d_in[3];
  const float* emb0 = (const float*)d_in[4];
  const float* emb1 = (const float*)d_in[5];
  const float* emb2 = (const float*)d_in[6];
  const float* emb3 = (const float*)d_in[7];
  const float* emb4 = (const float*)d_in[8];
  const float* emb5 = (const float*)d_in[9];
  const float* W1    = (const float*)d_in[10];
  const float* root1 = (const float*)d_in[11];
  const float* b1    = (const float*)d_in[12];
  const float* W2    = (const float*)d_in[13];  // [R,H,O] flat == [1024,256]
  const float* root2 = (const float*)d_in[14];
  const float* b2    = (const float*)d_in[15];
  const float* g1w   = (const float*)d_in[16];
  const float* g1b   = (const float*)d_in[17];
  const float* bng   = (const float*)d_in[18];
  const float* bnb   = (const float*)d_in[19];
  const float* g2w   = (const float*)d_in[20];
  const float* g2b   = (const float*)d_in[21];
  const float* glw   = (const float*)d_in[22];
  const float* glb   = (const float*)d_in[23];
  float* out = (float*)d_out;

  // ---- workspace carve-up (256B aligned), total ≈ 128 MB ----
  char* w = (char*)d_ws;
  auto alloc = [&](size_t bytes)->char* {
    char* p = w; w += (bytes + 255) & ~(size_t)255; return p;
  };
  char* gReg = alloc((size_t)NN*HD*sizeof(float));      // A1 (bf16), later g (f32)
  unsigned short* A1 = (unsigned short*)gReg;
  float* g = (float*)gReg;
  unsigned short* agg  = (unsigned short*)alloc((size_t)CHUNK*NR*HD*2);  // 20.5 MB
  unsigned short* h1   = (unsigned short*)alloc((size_t)NN*HD*2);        // 25.6 MB
  unsigned short* hRes = (unsigned short*)alloc((size_t)NN*HD*2);        // 25.6 MB
  int*   cnt  = (int*)alloc((size_t)NSEG*sizeof(int));
  int*   offs = (int*)alloc((size_t)(NSEG+1)*sizeof(int));
  int*   cursor=(int*)alloc((size_t)NSEG*sizeof(int));
  int*   bsum = (int*)alloc((size_t)SC_NB*sizeof(int));
  int*   boff = (int*)alloc((size_t)SC_NB*sizeof(int));
  int*   esrc = (int*)alloc((size_t)NE*sizeof(int));
  float* W1eff= (float*)alloc((size_t)200*HD*sizeof(float));
  float* R1eff= (float*)alloc((size_t)50*HD*sizeof(float));
  unsigned short* B1t  = (unsigned short*)alloc((size_t)256*256*2);
  unsigned short* BtL2 = (unsigned short*)alloc((size_t)256*1280*2);   // [root2 | W2] transposed
  unsigned short* g1wt = (unsigned short*)alloc((size_t)256*256*2);
  float* gate = (float*)alloc((size_t)NN*sizeof(float));
  int*   goffs= (int*)alloc((size_t)(NBATCH+1)*sizeof(int));
  float* chan = (float*)alloc((size_t)2*HD*sizeof(float));
  float* bnp  = (float*)alloc((size_t)2*HD*sizeof(float));

  // ---- zero init ----
  hipMemsetAsync(cnt,  0, (size_t)NSEG*sizeof(int), stream);
  hipMemsetAsync(chan, 0, (size_t)2*HD*sizeof(float), stream);

  // ---- folded layer-1 weights (fp32), then bf16 transposed weight assembly ----
  k_weff<<<NR*50, HD, 0, stream>>>(emb0,emb1,emb2,emb3,emb4,emb5, W1, 384*HD, W1eff);
  k_weff<<<50,    HD, 0, stream>>>(emb0,emb1,emb2,emb3,emb4,emb5, root1, 0, R1eff);
  k_b1t<<<256, 256, 0, stream>>>(W1eff, R1eff, B1t);
  k_tconv<<<256, 256, 0, stream>>>(root2, BtL2, 256, 256, 1280, 0);
  k_tconv<<<1024, 256, 0, stream>>>(W2, BtL2, 1024, 256, 1280, 256);
  k_tconv<<<256, 256, 0, stream>>>(g1w, g1wt, 256, 256, 256, 0);

  // ---- CSR build (counts -> scan -> bin) ----
  k_cnt<<<(NE+255)/256, 256, 0, stream>>>(ei, et, cnt);
  k_scan1<<<SC_NB, SC_T, 0, stream>>>(cnt, bsum);
  k_scan2<<<1, 256, 0, stream>>>(bsum, boff, offs);
  k_scan3<<<SC_NB, SC_T, 0, stream>>>(cnt, boff, offs, cursor);
  k_bin<<<(NE+255)/256, 256, 0, stream>>>(ei, et, cursor, esrc);

  // ---- A1 from CSR gather (replaces scatter histogram) ----
  k_buildseg<<<NN, 256, 0, stream>>>(x, offs, esrc, A1);

  // ---- per-graph offsets (independent) ----
  k_goffs<<<(NN+255)/256, 256, 0, stream>>>(batch, goffs);

  // ---- layer 1 GEMM: h1 = sigmoid(A1 @ B1 + b1) ----
  dim3 gFull(2, (NN+127)/128);
  k_mfma<<<gFull, 256, 0, stream>>>(A1, 256, 256, nullptr, 0, B1t, b1, h1, nullptr, NN, 256, 1);

  // ---- layer 2: chunked agg + dual-A K=1280 GEMM ([h1 | agg] @ [root2;W2]) + sigmoid ----
  for (int c0 = 0; c0 < NN; c0 += CHUNK){
    int m = min(CHUNK, NN - c0);
    k_agg<<<(m*64+255)/256, 256, 0, stream>>>(offs, esrc, h1, agg, c0, m);
    dim3 gC(2, (m+127)/128);
    k_mfma<<<gC, 256, 0, stream>>>(h1 + (size_t)c0*HD, 256, 256, agg, NR*HD,
                                   BtL2, b2, hRes + (size_t)c0*HD, nullptr, m, 1280, 1);
  }
  // hRes = h2 (bf16)

  // ---- gate linear: g = h2 @ g1w + g1b (fp32 out), BN stats ----
  k_mfma<<<gFull, 256, 0, stream>>>(hRes, 256, 256, nullptr, 0, g1wt, g1b, nullptr, g, NN, 256, 0);
  k_bnstats<<<(NN+127)/128, HD, 0, stream>>>(g, chan);
  k_bnfin<<<1, HD, 0, stream>>>(chan, bng, bnb, bnp);

  // ---- gate scalar (no atomics) + fused per-graph softmax/pool/output ----
  k_gate<<<(NN+3)/4, 256, 0, stream>>>(g, bnp, g2w, g2b, gate);
  k_poolg<<<NBATCH, 256, 0, stream>>>(hRes, gate, goffs, glw, glb, out);
}